// Round 11
// baseline (651.121 us; speedup 1.0000x reference)
//
#include <hip/hip_runtime.h>
#include <hip/hip_bf16.h>
#include <math.h>

typedef __attribute__((ext_vector_type(8))) short short8;
typedef __attribute__((ext_vector_type(4))) float f32x4;
typedef __attribute__((ext_vector_type(16))) float f32x16;
typedef __attribute__((ext_vector_type(4))) unsigned int u32x4;
typedef __attribute__((ext_vector_type(2))) int i32x2;

#define BATCH   2
#define SLEN    2048
#define DMODEL  4096
#define NHEADS  32
#define KVHEADS 8
#define HD      128
#define KVDIM   (KVHEADS*HD)   // 1024
#define MROWS   (BATCH*SLEN)   // 4096
#define NQKV    (DMODEL + 2*KVDIM)   // 6144

// async global->LDS, 16B per lane, dest = wave-uniform base + lane*16
#define GLDS16(gp, lp) __builtin_amdgcn_global_load_lds( \
    (const __attribute__((address_space(1))) void*)(gp), \
    (__attribute__((address_space(3))) void*)(lp), 16, 0, 0)

static __device__ __forceinline__ unsigned short bf16bits(float x) {
    __hip_bfloat16 h = __float2bfloat16(x);
    return *(unsigned short*)&h;
}
static __device__ __forceinline__ float bf2f(unsigned short u) {
    __hip_bfloat16 h = *(__hip_bfloat16*)&u;
    return __bfloat162float(h);
}
// v_cvt_pk_bf16_f32: lo=src0, hi=src1 (no builtin on gfx950)
static __device__ __forceinline__ unsigned cvtpk(float a, float b) {
    unsigned r;
    asm("v_cvt_pk_bf16_f32 %0, %1, %2" : "=v"(r) : "v"(a), "v"(b));
    return r;
}

// ---------------- fp32 -> bf16 cast ----------------
__global__ __launch_bounds__(256) void cast_k(const float* __restrict__ in,
                                              unsigned short* __restrict__ out, long n) {
    long i = ((long)blockIdx.x * 256 + threadIdx.x) * 4;
    if (i >= n) return;
    float4 v = *(const float4*)(in + i);
    union { unsigned short h[4]; uint2 u; } c;
    c.h[0] = bf16bits(v.x); c.h[1] = bf16bits(v.y);
    c.h[2] = bf16bits(v.z); c.h[3] = bf16bits(v.w);
    *(uint2*)(out + i) = c.u;
}

// ---------------- RoPE tables ----------------
__global__ void rope_table_k(const int* __restrict__ pos,
                             float* __restrict__ cosT, float* __restrict__ sinT) {
    int s = blockIdx.x;
    int d = threadIdx.x;
    float p = (float)pos[s];
    float inv = powf(10000.0f, -(float)(2 * d) / 128.0f);
    float ang = p * inv;
    cosT[s * 64 + d] = cosf(ang);
    sinT[s * 64 + d] = sinf(ang);
}

// ---------------- RoPE apply in-place on bf16, row stride ld ----------------
__global__ void rope_bf_k(unsigned short* __restrict__ x,
                          const float* __restrict__ cosT, const float* __restrict__ sinT,
                          int nh, int ld, float mul) {
    int idx = blockIdx.x * 256 + threadIdx.x;
    int d = idx & 63;
    int rest = idx >> 6;
    int h = rest % nh;
    int row = rest / nh;
    int s = row & (SLEN - 1);
    float c  = cosT[s * 64 + d] * mul;
    float sn = sinT[s * 64 + d] * mul;
    unsigned short* base = x + (size_t)row * ld + h * HD;
    float x1 = bf2f(base[d]), x2 = bf2f(base[d + 64]);
    base[d]      = bf16bits(x1 * c - x2 * sn);
    base[d + 64] = bf16bits(x2 * c + x1 * sn);
}

// ---------------- V transpose: bf16 [M][ldv] -> bf16 Vt[b*KVH+kvh][d=128][s=2048] ----------------
__global__ __launch_bounds__(256) void vtrans_k(const unsigned short* __restrict__ V, int ldv,
                                                unsigned short* __restrict__ Vt) {
    __shared__ unsigned short L[64][144];
    const int t = threadIdx.x;
    const int s0 = blockIdx.x * 64;
    const int bk = blockIdx.y;              // b*KVH + kvh
    const int b = bk >> 3, kvh = bk & 7;
    #pragma unroll
    for (int j = 0; j < 4; ++j) {
        int idx = t + j * 256;
        int row = idx >> 4;
        int c8  = (idx & 15) * 8;
        *(short8*)&L[row][c8] =
            *(const short8*)(V + ((size_t)b * SLEN + s0 + row) * ldv + kvh * HD + c8);
    }
    __syncthreads();
    {
        int d  = t >> 1;
        int sh = (t & 1) * 32;
        unsigned short tmp[32];
        #pragma unroll
        for (int j = 0; j < 32; ++j) tmp[j] = L[sh + j][d];
        unsigned short* dst = Vt + ((size_t)bk * HD + d) * SLEN + s0 + sh;
        #pragma unroll
        for (int j = 0; j < 4; ++j)
            *(short8*)(dst + j * 8) = *(const short8*)(tmp + j * 8);
    }
}

// ---------------- 256x256 bf16 MFMA GEMM-NT, BK=64, 8 waves, 4-phase interleave ----------------
// Per K-tile: 4 phases {ds_read A-quad (+B at q0) | stage part of tile t+1 | barrier |
// 16 MFMA | barrier}. Stage distribution: q0=B0, q1=B1, q2=A0+A1, q3=none; a single
// vmcnt(0) after q3's MFMA (>=1 full phase after last issue -> cheap) guarantees all of
// tile t+1 is resident before its phase-0 reads. No loads left in flight across reads.
// LDS halves [128][64] slot^=(row&7) XOR swizzle (conflict-free, verified r8/r9).
// XCD chunking: rectangular 8 x (chunk/8) tile blocks per XCD (bijective for our grids).
template<typename CT>
__global__ __launch_bounds__(512, 1) void gemm256(
    const unsigned short* __restrict__ A, int lda,
    const unsigned short* __restrict__ W, int ldw,
    CT* __restrict__ C, int ldc,
    int M, int N, int K)
{
    __shared__ unsigned short Asl[2][2][128 * 64];   // [buf][half][row*64 + col]
    __shared__ unsigned short Bsl[2][2][128 * 64];

    const int t = threadIdx.x;           // 0..511
    const int w = t >> 6, lane = t & 63;

    // rectangular per-XCD chunking: XCD x owns an 8 x rn rectangle of 256-tiles
    const int gx = gridDim.x;
    const int nwg = gx * gridDim.y;
    const int chunk = nwg >> 3;          // tiles per XCD
    const int orig = blockIdx.y * gx + blockIdx.x;
    const int xcd = orig & 7, idx = orig >> 3;
    const int rn = chunk >> 3;           // rect n-width (QKV:6, O:4)
    const int nrx = gx / rn;             // rect grid cols
    const int rx = xcd % nrx, ry = xcd / nrx;
    const int iy = idx / rn, ix = idx % rn;
    const int m0 = (ry * 8 + iy) * 256;
    const int n0 = (rx * rn + ix) * 256;

    const int wm = (w >> 2) * 128;       // 0 / 128
    const int wn = (w & 3) * 64;         // 0,64,128,192
    const int fr = lane & 15, hi = lane >> 4;

    f32x4 acc[8][4];
    #pragma unroll
    for (int i = 0; i < 8; ++i)
        #pragma unroll
        for (int j = 0; j < 4; ++j)
            acc[i][j] = (f32x4){0.f, 0.f, 0.f, 0.f};

    // staging geometry: thread covers (row = j*64 + sr, slot = sl), dest linear in lane
    const int sr = t >> 3;
    const int sl = t & 7;
    const int wv512 = w * 512;

    // ---- prologue: stage tile 0 fully, drain, barrier
    {
        #pragma unroll
        for (int hh = 0; hh < 4; ++hh) {
            #pragma unroll
            for (int j = 0; j < 2; ++j) {
                const int row = j * 64 + sr;
                const int scol = (sl ^ (row & 7)) << 3;
                if (hh < 2)
                    GLDS16(W + (size_t)(n0 + hh * 128 + row) * ldw + scol,
                           &Bsl[0][hh][j * 4096 + wv512]);
                else
                    GLDS16(A + (size_t)(m0 + (hh - 2) * 128 + row) * lda + scol,
                           &Asl[0][hh - 2][j * 4096 + wv512]);
            }
        }
        asm volatile("s_waitcnt vmcnt(0)" ::: "memory");
        __builtin_amdgcn_s_barrier();
        __builtin_amdgcn_sched_barrier(0);
    }

    const int NT = K >> 6;
    int buf = 0;
    for (int kt = 0; kt < NT; ++kt) {
        const unsigned short* Ah = Asl[buf][w >> 2];
        const unsigned short* Bh = Bsl[buf][(w & 3) >> 1];
        const bool pf = (kt + 1 < NT);
        const int k0n = (kt + 1) << 6;
        short8 bfr[4][2];

        #pragma unroll
        for (int q = 0; q < 4; ++q) {
            // ---- ds-reads for this phase
            if (q == 0) {
                #pragma unroll
                for (int j = 0; j < 4; ++j) {
                    const int lr = (wn & 127) + j * 16 + fr;
                    const int sz = lr & 7;
                    bfr[j][0] = *(const short8*)&Bh[lr * 64 + (((0 + hi) ^ sz) << 3)];
                    bfr[j][1] = *(const short8*)&Bh[lr * 64 + (((4 + hi) ^ sz) << 3)];
                }
            }
            short8 af[2][2];
            #pragma unroll
            for (int ii = 0; ii < 2; ++ii) {
                const int lr = q * 32 + ii * 16 + fr;
                const int sz = lr & 7;
                af[ii][0] = *(const short8*)&Ah[lr * 64 + (((0 + hi) ^ sz) << 3)];
                af[ii][1] = *(const short8*)&Ah[lr * 64 + (((4 + hi) ^ sz) << 3)];
            }

            // ---- stage tile kt+1: q0=B0, q1=B1, q2=A0+A1, q3=none
            if (pf) {
                if (q < 2) {
                    #pragma unroll
                    for (int j = 0; j < 2; ++j) {
                        const int row = j * 64 + sr;
                        const int scol = k0n + ((sl ^ (row & 7)) << 3);
                        GLDS16(W + (size_t)(n0 + q * 128 + row) * ldw + scol,
                               &Bsl[buf ^ 1][q][j * 4096 + wv512]);
                    }
                } else if (q == 2) {
                    #pragma unroll
                    for (int half = 0; half < 2; ++half)
                        #pragma unroll
                        for (int j = 0; j < 2; ++j) {
                            const int row = j * 64 + sr;
                            const int scol = k0n + ((sl ^ (row & 7)) << 3);
                            GLDS16(A + (size_t)(m0 + half * 128 + row) * lda + scol,
                                   &Asl[buf ^ 1][half][j * 4096 + wv512]);
                        }
                }
            }

            __builtin_amdgcn_sched_barrier(0);
            __builtin_amdgcn_s_barrier();
            __builtin_amdgcn_sched_barrier(0);

            // ---- 16 MFMA (quadrant q) — compiler inserts fine-grained lgkmcnt
            __builtin_amdgcn_s_setprio(1);
            #pragma unroll
            for (int ii = 0; ii < 2; ++ii)
                #pragma unroll
                for (int j = 0; j < 4; ++j) {
                    acc[q * 2 + ii][j] = __builtin_amdgcn_mfma_f32_16x16x32_bf16(
                        af[ii][0], bfr[j][0], acc[q * 2 + ii][j], 0, 0, 0);
                    acc[q * 2 + ii][j] = __builtin_amdgcn_mfma_f32_16x16x32_bf16(
                        af[ii][1], bfr[j][1], acc[q * 2 + ii][j], 0, 0, 0);
                }
            __builtin_amdgcn_s_setprio(0);

            // ---- drain next tile's loads once, >=1 phase after last issue (q2)
            if (q == 3 && pf)
                asm volatile("s_waitcnt vmcnt(0)" ::: "memory");

            __builtin_amdgcn_sched_barrier(0);
            __builtin_amdgcn_s_barrier();
            __builtin_amdgcn_sched_barrier(0);
        }
        buf ^= 1;
    }

    // epilogue: C/D layout col=lane&15, row=(lane>>4)*4+reg (verified)
    const int crow = (lane >> 4) * 4, ccol = lane & 15;
    #pragma unroll
    for (int i = 0; i < 8; ++i)
        #pragma unroll
        for (int j = 0; j < 4; ++j) {
            CT* cp = C + (size_t)(m0 + wm + i * 16 + crow) * ldc + (n0 + wn + j * 16 + ccol);
            #pragma unroll
            for (int r = 0; r < 4; ++r) {
                if constexpr (sizeof(CT) == 2)
                    cp[(size_t)r * ldc] = bf16bits(acc[i][j][r]);
                else
                    cp[(size_t)r * ldc] = acc[i][j][r];
            }
        }
}

// ---------------- MFMA flash attention: swapped 32x32x16, in-register softmax,
// LDS-shared double-buffered K/V with counted vmcnt (verified r8) ----------------
__global__ __launch_bounds__(256, 2) void flash_mfma32(
    const unsigned short* __restrict__ Qb, int ldq,   // rope'd, pre-scaled
    const unsigned short* __restrict__ Kb, int ldk,   // rope'd
    const unsigned short* __restrict__ Vt,            // [B*KVH][HD][SLEN]
    unsigned short* __restrict__ Ob)                  // [MROWS][DMODEL]
{
    __shared__ unsigned short Ks[2][64 * 128];   // [kv 64][d 128], rows 256B, swz (row&15)<<4
    __shared__ unsigned short Vs[2][128 * 64];   // [d 128][kv 64], rows 128B, swz (row&7)<<4

    const int t = threadIdx.x;
    const int wid = t >> 6, lane = t & 63;
    const int qt = (int)gridDim.x - 1 - (int)blockIdx.x;   // heavy blocks first
    const int bh = blockIdx.y;
    const int b = bh >> 5, h = bh & 31, kvh = h >> 2;
    const int lq = lane & 31;
    const int hl = lane >> 5;
    const int qw0 = qt * 128 + wid * 32;
    const int qg = qw0 + lq;
    const size_t qrowg = (size_t)b * SLEN + qg;

    const unsigned short* Kg0 = Kb + (size_t)b * SLEN * ldk + kvh * HD;
    const unsigned short* Vg0 = Vt + (size_t)(b * KVHEADS + kvh) * HD * SLEN;

    auto STAGE = [&](int buf, int kt) {   // 8 GLDS16 per thread
        const unsigned short* Kg = Kg0 + (size_t)kt * 64 * ldk;
        #pragma unroll
        for (int i = 0; i < 4; ++i) {
            int row = i * 16 + (t >> 4);
            int colel = ((((t & 15) << 4) ^ ((row & 15) << 4)) >> 1);
            GLDS16(Kg + (size_t)row * ldk + colel, &Ks[buf][i * 2048 + wid * 512]);
        }
        const unsigned short* Vg = Vg0 + kt * 64;
        #pragma unroll
        for (int i = 0; i < 4; ++i) {
            int row = i * 32 + (t >> 3);
            int colel = ((((t & 7) << 4) ^ ((row & 7) << 4)) >> 1);
            GLDS16(Vg + (size_t)row * SLEN + colel, &Vs[buf][i * 2048 + wid * 512]);
        }
    };

    STAGE(0, 0);
    short8 qf[8];
    {
        const unsigned short* qp = Qb + qrowg * ldq + h * HD + hl * 8;
        #pragma unroll
        for (int dt = 0; dt < 8; ++dt)
            qf[dt] = *(const short8*)(qp + dt * 16);
    }

    f32x16 accO[4];
    #pragma unroll
    for (int db = 0; db < 4; ++db)
        #pragma unroll
        for (int r = 0; r < 16; ++r) accO[db][r] = 0.f;
    float m_i = -INFINITY, l_i = 0.f;

    const int ntmax = 2 * qt + 2;   // uniform across waves
    int p = 0;
    for (int kt = 0; kt < ntmax; ++kt) {
        if (kt + 1 < ntmax) {
            STAGE(p ^ 1, kt + 1);
            asm volatile("s_waitcnt vmcnt(8)" ::: "memory");
        } else {
            asm volatile("s_waitcnt vmcnt(0)" ::: "memory");
        }
        __builtin_amdgcn_s_barrier();
        __builtin_amdgcn_sched_barrier(0);

        const unsigned short* Kp = Ks[p];
        const unsigned short* Vp = Vs[p];

        // ---- QK^T: S^T[kv 64][q 32], 16 MFMA
        f32x16 sc[2];
        #pragma unroll
        for (int blk = 0; blk < 2; ++blk) {
            #pragma unroll
            for (int r = 0; r < 16; ++r) sc[blk][r] = 0.f;
            __builtin_amdgcn_s_setprio(1);
            #pragma unroll
            for (int dt = 0; dt < 8; ++dt) {
                int krow = blk * 32 + lq;
                int kb = krow * 256 + ((dt * 32 + hl * 16) ^ ((krow & 15) << 4));
                short8 kf = *(const short8*)(Kp + (kb >> 1));
                sc[blk] = __builtin_amdgcn_mfma_f32_32x32x16_bf16(kf, qf[dt], sc[blk], 0, 0, 0);
            }
            __builtin_amdgcn_s_setprio(0);
        }

        // ---- causal mask
        if (kt * 64 + 63 > qw0) {
            #pragma unroll
            for (int blk = 0; blk < 2; ++blk)
                #pragma unroll
                for (int r = 0; r < 16; ++r) {
                    int kv = kt * 64 + blk * 32 + (r & 3) + 8 * (r >> 2) + 4 * hl;
                    if (kv > qg) sc[blk][r] = -INFINITY;
                }
        }

        // ---- row max (in-lane + one cross-half swap)
        float pmax = sc[0][0];
        #pragma unroll
        for (int r = 1; r < 16; ++r) pmax = fmaxf(pmax, sc[0][r]);
        #pragma unroll
        for (int r = 0; r < 16; ++r) pmax = fmaxf(pmax, sc[1][r]);
        {
            i32x2 mr = __builtin_amdgcn_permlane32_swap(__float_as_int(pmax), __float_as_int(pmax), false, false);
            pmax = fmaxf(__int_as_float(mr.x), __int_as_float(mr.y));
        }

        // ---- defer-max rescale (THR=8 log2 -> P<=256)
        if (!__all(pmax <= m_i + 8.0f)) {
            float mn = fmaxf(m_i, pmax);
            float al = exp2f(m_i - mn);
            m_i = mn;
            l_i *= al;
            #pragma unroll
            for (int db = 0; db < 4; ++db)
                #pragma unroll
                for (int r = 0; r < 16; ++r) accO[db][r] *= al;
        }

        // ---- exp + row sum
        float rs = 0.f;
        #pragma unroll
        for (int blk = 0; blk < 2; ++blk)
            #pragma unroll
            for (int r = 0; r < 16; ++r) {
                float pv = exp2f(sc[blk][r] - m_i);
                sc[blk][r] = pv;
                rs += pv;
            }
        {
            i32x2 sr = __builtin_amdgcn_permlane32_swap(__float_as_int(rs), __float_as_int(rs), false, false);
            rs = __int_as_float(sr.x) + __int_as_float(sr.y);
        }
        l_i += rs;

        // ---- pack P -> PV B-fragments in registers (verified r7)
        short8 pf[4];
        #pragma unroll
        for (int blk = 0; blk < 2; ++blk) {
            unsigned c01 = cvtpk(sc[blk][0],  sc[blk][1]);
            unsigned c23 = cvtpk(sc[blk][2],  sc[blk][3]);
            unsigned c45 = cvtpk(sc[blk][4],  sc[blk][5]);
            unsigned c67 = cvtpk(sc[blk][6],  sc[blk][7]);
            i32x2 sA = __builtin_amdgcn_permlane32_swap((int)c01, (int)c45, false, false);
            i32x2 sB = __builtin_amdgcn_permlane32_swap((int)c23, (int)c67, false, false);
            u32x4 f0 = {(unsigned)sA.x, (unsigned)sB.x, (unsigned)sA.y, (unsigned)sB.y};
            pf[blk * 2] = *(short8*)&f0;
            unsigned c89 = cvtpk(sc[blk][8],  sc[blk][9]);
            unsigned cab = cvtpk(sc[blk][10], sc[blk][11]);
            unsigned ccd = cvtpk(sc[blk][12], sc[blk][13]);
            unsigned cef = cvtpk(sc[blk][14], sc[blk][15]);
            i32x2 sC = __builtin_amdgcn_permlane32_swap((int)c89, (int)ccd, false, false);
            i32x2 sD = __builtin_amdgcn_permlane32_swap((int)cab, (int)cef, false, false);
            u32x4 f1 = {(unsigned)sC.x, (unsigned)sD.x, (unsigned)sC.y, (unsigned)sD.y};
            pf[blk * 2 + 1] = *(short8*)&f1;
        }

        // ---- PV: O^T[d][q] accum, 16 MFMA
        #pragma unroll
        for (int db = 0; db < 4; ++db) {
            __builtin_amdgcn_s_setprio(1);
            #pragma unroll
            for (int ks = 0; ks < 4; ++ks) {
                int vrow = db * 32 + lq;
                int vb = vrow * 128 + ((ks * 32 + hl * 16) ^ ((vrow & 7) << 4));
                short8 vf = *(const short8*)(Vp + (vb >> 1));
                accO[db] = __builtin_amdgcn_mfma_f32_32x32x16_bf16(vf, pf[ks], accO[db], 0, 0, 0);
            }
            __builtin_amdgcn_s_setprio(0);
        }

        __builtin_amdgcn_sched_barrier(0);
        __builtin_amdgcn_s_barrier();
        p ^= 1;
    }

    // ---- epilogue
    float inv = 1.0f / l_i;
    unsigned short* orow = Ob + qrowg * DMODEL + h * HD;
    #pragma unroll
    for (int db = 0; db < 4; ++db)
        #pragma unroll
        for (int rq = 0; rq < 4; ++rq) {
            unsigned w0 = cvtpk(accO[db][rq * 4 + 0] * inv, accO[db][rq * 4 + 1] * inv);
            unsigned w1 = cvtpk(accO[db][rq * 4 + 2] * inv, accO[db][rq * 4 + 3] * inv);
            uint2 pkd; pkd.x = w0; pkd.y = w1;
            *(uint2*)(orow + db * 32 + rq * 8 + hl * 4) = pkd;
        }
}

extern "C" void kernel_launch(void* const* d_in, const int* in_sizes, int n_in,
                              void* d_out, int out_size, void* d_ws, size_t ws_size,
                              hipStream_t stream) {
    const float* hs  = (const float*)d_in[0];
    const int*   pos = (const int*)d_in[1];
    const float* wq  = (const float*)d_in[2];
    const float* wk  = (const float*)d_in[3];
    const float* wv  = (const float*)d_in[4];
    const float* wo  = (const float*)d_in[5];
    float* out = (float*)d_out;

    char* ws = (char*)d_ws;
    unsigned short* hs_bf   = (unsigned short*)(ws);                        // 32 MB
    unsigned short* wqkv_bf = (unsigned short*)(ws + ((size_t)32  << 20));  // 48 MB [6144][4096]
    unsigned short* wo_bf   = (unsigned short*)(ws + ((size_t)80  << 20));  // 32 MB
    unsigned short* qkv_bf  = (unsigned short*)(ws + ((size_t)112 << 20));  // 48 MB [4096][6144]
    unsigned short* Vtb     = (unsigned short*)(ws + ((size_t)160 << 20));  // 8 MB
    unsigned short* Obf     = (unsigned short*)(ws + ((size_t)168 << 20));  // 32 MB
    float*          cosT    = (float*)(ws + ((size_t)200 << 20));           // 512 KB
    float*          sinT    = (float*)(ws + ((size_t)200 << 20) + (size_t)SLEN * 64 * 4);
    // total ~201 MB

    const long nHS = (long)MROWS * DMODEL;
    const long nWQ = (long)DMODEL * DMODEL;
    const long nWK = (long)KVDIM * DMODEL;

    rope_table_k<<<SLEN, 64, 0, stream>>>(pos, cosT, sinT);

    cast_k<<<nHS / 4 / 256, 256, 0, stream>>>(hs, hs_bf, nHS);
    cast_k<<<nWQ / 4 / 256, 256, 0, stream>>>(wq, wqkv_bf, nWQ);
    cast_k<<<nWK / 4 / 256, 256, 0, stream>>>(wk, wqkv_bf + (size_t)DMODEL * DMODEL, nWK);
    cast_k<<<nWK / 4 / 256, 256, 0, stream>>>(wv, wqkv_bf + (size_t)(DMODEL + KVDIM) * DMODEL, nWK);
    cast_k<<<nWQ / 4 / 256, 256, 0, stream>>>(wo, wo_bf, nWQ);

    // fused QKV projection: [4096][6144] bf16
    gemm256<unsigned short><<<dim3(NQKV/256, MROWS/256), 512, 0, stream>>>(
        hs_bf, DMODEL, wqkv_bf, DMODEL, qkv_bf, NQKV, MROWS, NQKV, DMODEL);

    // Q gets (1/sqrt(128)) * log2(e) folded in; K unscaled
    const float qmul = 0.088388347648318447f * 1.4426950408889634f;
    rope_bf_k<<<(MROWS * NHEADS  * 64) / 256, 256, 0, stream>>>(qkv_bf,          cosT, sinT, NHEADS,  NQKV, qmul);
    rope_bf_k<<<(MROWS * KVHEADS * 64) / 256, 256, 0, stream>>>(qkv_bf + DMODEL, cosT, sinT, KVHEADS, NQKV, 1.0f);
    vtrans_k<<<dim3(SLEN/64, BATCH*KVHEADS), 256, 0, stream>>>(qkv_bf + DMODEL + KVDIM, NQKV, Vtb);

    flash_mfma32<<<dim3(SLEN/128, BATCH*NHEADS), 256, 0, stream>>>(
        qkv_bf, NQKV, qkv_bf + DMODEL, NQKV, Vtb, Obf);

    gemm256<float><<<dim3(DMODEL/256, MROWS/256), 512, 0, stream>>>(
        Obf, DMODEL, wo_bf, DMODEL, out, DMODEL, MROWS, DMODEL, DMODEL);
}

// Round 12
// 625.367 us; speedup vs baseline: 1.0412x; 1.0412x over previous
//
#include <hip/hip_runtime.h>
#include <hip/hip_bf16.h>
#include <math.h>

typedef __attribute__((ext_vector_type(8))) short short8;
typedef __attribute__((ext_vector_type(4))) float f32x4;
typedef __attribute__((ext_vector_type(16))) float f32x16;
typedef __attribute__((ext_vector_type(4))) unsigned int u32x4;
typedef __attribute__((ext_vector_type(2))) int i32x2;

#define BATCH   2
#define SLEN    2048
#define DMODEL  4096
#define NHEADS  32
#define KVHEADS 8
#define HD      128
#define KVDIM   (KVHEADS*HD)   // 1024
#define MROWS   (BATCH*SLEN)   // 4096
#define NQKV    (DMODEL + 2*KVDIM)   // 6144

// async global->LDS, 16B per lane, dest = wave-uniform base + lane*16
#define GLDS16(gp, lp) __builtin_amdgcn_global_load_lds( \
    (const __attribute__((address_space(1))) void*)(gp), \
    (__attribute__((address_space(3))) void*)(lp), 16, 0, 0)

static __device__ __forceinline__ unsigned short bf16bits(float x) {
    __hip_bfloat16 h = __float2bfloat16(x);
    return *(unsigned short*)&h;
}
static __device__ __forceinline__ float bf2f(unsigned short u) {
    __hip_bfloat16 h = *(__hip_bfloat16*)&u;
    return __bfloat162float(h);
}
// v_cvt_pk_bf16_f32: lo=src0, hi=src1 (no builtin on gfx950)
static __device__ __forceinline__ unsigned cvtpk(float a, float b) {
    unsigned r;
    asm("v_cvt_pk_bf16_f32 %0, %1, %2" : "=v"(r) : "v"(a), "v"(b));
    return r;
}

// ---------------- fp32 -> bf16 cast ----------------
__global__ __launch_bounds__(256) void cast_k(const float* __restrict__ in,
                                              unsigned short* __restrict__ out, long n) {
    long i = ((long)blockIdx.x * 256 + threadIdx.x) * 4;
    if (i >= n) return;
    float4 v = *(const float4*)(in + i);
    union { unsigned short h[4]; uint2 u; } c;
    c.h[0] = bf16bits(v.x); c.h[1] = bf16bits(v.y);
    c.h[2] = bf16bits(v.z); c.h[3] = bf16bits(v.w);
    *(uint2*)(out + i) = c.u;
}

// ---------------- RoPE tables ----------------
__global__ void rope_table_k(const int* __restrict__ pos,
                             float* __restrict__ cosT, float* __restrict__ sinT) {
    int s = blockIdx.x;
    int d = threadIdx.x;
    float p = (float)pos[s];
    float inv = powf(10000.0f, -(float)(2 * d) / 128.0f);
    float ang = p * inv;
    cosT[s * 64 + d] = cosf(ang);
    sinT[s * 64 + d] = sinf(ang);
}

// ---------------- RoPE apply in-place on bf16, row stride ld ----------------
__global__ void rope_bf_k(unsigned short* __restrict__ x,
                          const float* __restrict__ cosT, const float* __restrict__ sinT,
                          int nh, int ld, float mul) {
    int idx = blockIdx.x * 256 + threadIdx.x;
    int d = idx & 63;
    int rest = idx >> 6;
    int h = rest % nh;
    int row = rest / nh;
    int s = row & (SLEN - 1);
    float c  = cosT[s * 64 + d] * mul;
    float sn = sinT[s * 64 + d] * mul;
    unsigned short* base = x + (size_t)row * ld + h * HD;
    float x1 = bf2f(base[d]), x2 = bf2f(base[d + 64]);
    base[d]      = bf16bits(x1 * c - x2 * sn);
    base[d + 64] = bf16bits(x2 * c + x1 * sn);
}

// ---------------- V transpose: bf16 [M][ldv] -> bf16 Vt[b*KVH+kvh][d=128][s=2048] ----------------
__global__ __launch_bounds__(256) void vtrans_k(const unsigned short* __restrict__ V, int ldv,
                                                unsigned short* __restrict__ Vt) {
    __shared__ unsigned short L[64][144];
    const int t = threadIdx.x;
    const int s0 = blockIdx.x * 64;
    const int bk = blockIdx.y;              // b*KVH + kvh
    const int b = bk >> 3, kvh = bk & 7;
    #pragma unroll
    for (int j = 0; j < 4; ++j) {
        int idx = t + j * 256;
        int row = idx >> 4;
        int c8  = (idx & 15) * 8;
        *(short8*)&L[row][c8] =
            *(const short8*)(V + ((size_t)b * SLEN + s0 + row) * ldv + kvh * HD + c8);
    }
    __syncthreads();
    {
        int d  = t >> 1;
        int sh = (t & 1) * 32;
        unsigned short tmp[32];
        #pragma unroll
        for (int j = 0; j < 32; ++j) tmp[j] = L[sh + j][d];
        unsigned short* dst = Vt + ((size_t)bk * HD + d) * SLEN + s0 + sh;
        #pragma unroll
        for (int j = 0; j < 4; ++j)
            *(short8*)(dst + j * 8) = *(const short8*)(tmp + j * 8);
    }
}

// ---------------- 256x256 bf16 MFMA GEMM-NT, BK=64, 8 waves, derived-waits 4-phase ----------------
// Stage tile t+1 in 8 FIFO units (1 load/thread): B-u0,B-u1@q0, B-u2,B-u3@q1,
// A-u0,A-u1@q2, A-u2,A-u3@q3. A-unit u = rows u*32..+31 of BOTH halves = exactly what
// compute phase q reads; B-unit (w&3) read only at q0. Waits (wait THEN barrier -> global):
//   q0: vmcnt(3)  [all B + A-u0 landed; A-u1..3 in flight]
//   q1: vmcnt(4)  [A-u1 landed]        (last tile: 2)
//   q2: vmcnt(4)  [A-u2,A-u3 landed]   (last tile: 1)
//   q3: none                            (last tile: vmcnt(0)+barrier)
// Never drains mid-stream; 3 barriers/K-tile. LDS [128][64] halves, slot^=(row&7) swizzle.
// XCD chunking: rectangular 8 x (chunk/8) tile blocks per XCD.
template<typename CT>
__global__ __launch_bounds__(512, 1) void gemm256(
    const unsigned short* __restrict__ A, int lda,
    const unsigned short* __restrict__ W, int ldw,
    CT* __restrict__ C, int ldc,
    int M, int N, int K)
{
    __shared__ unsigned short Asl[2][2][128 * 64];   // [buf][half][row*64 + col]
    __shared__ unsigned short Bsl[2][2][128 * 64];

    const int t = threadIdx.x;           // 0..511
    const int w = t >> 6, lane = t & 63;

    // rectangular per-XCD chunking
    const int gx = gridDim.x;
    const int nwg = gx * gridDim.y;
    const int chunk = nwg >> 3;
    const int orig = blockIdx.y * gx + blockIdx.x;
    const int xcd = orig & 7, idx = orig >> 3;
    const int rn = chunk >> 3;
    const int nrx = gx / rn;
    const int rx = xcd % nrx, ry = xcd / nrx;
    const int iy = idx / rn, ix = idx % rn;
    const int m0 = (ry * 8 + iy) * 256;
    const int n0 = (rx * rn + ix) * 256;

    const int wm = (w >> 2) * 128;
    const int wn = (w & 3) * 64;
    const int fr = lane & 15, hi = lane >> 4;

    f32x4 acc[8][4];
    #pragma unroll
    for (int i = 0; i < 8; ++i)
        #pragma unroll
        for (int j = 0; j < 4; ++j)
            acc[i][j] = (f32x4){0.f, 0.f, 0.f, 0.f};

    const int sl = t & 7;
    const int srw = (t >> 3) & 7;        // swizzle row bits (same for A/B units)
    const int wv512 = w * 512;

    // stage unit helpers: 1 GLDS16 per thread each
    auto STAGE_B = [&](int bufn, int k0, int u) {
        const int row = u * 64 + (t >> 3);                       // N-row 0..255
        const int scol = k0 + ((sl ^ srw) << 3);
        GLDS16(W + (size_t)(n0 + row) * ldw + scol,
               &Bsl[bufn][u >> 1][(u & 1) * 4096 + wv512]);
    };
    auto STAGE_A = [&](int bufn, int k0, int u) {
        const int half = w >> 2;
        const int row = half * 128 + u * 32 + ((t & 255) >> 3);  // M-row
        const int scol = k0 + ((sl ^ srw) << 3);
        GLDS16(A + (size_t)(m0 + row) * lda + scol,
               &Asl[bufn][half][u * 2048 + (w & 3) * 512]);
    };

    // ---- prologue: stage tile 0, FIFO order B0..B3, A0..A3
    STAGE_B(0, 0, 0); STAGE_B(0, 0, 1); STAGE_B(0, 0, 2); STAGE_B(0, 0, 3);
    STAGE_A(0, 0, 0); STAGE_A(0, 0, 1); STAGE_A(0, 0, 2); STAGE_A(0, 0, 3);

    const int NT = K >> 6;
    int buf = 0;
    for (int kt = 0; kt < NT; ++kt) {
        const bool pf = (kt + 1 < NT);
        const int k0n = (kt + 1) << 6;
        const unsigned short* Ah = Asl[buf][w >> 2];
        const unsigned short* Bh = Bsl[buf][(w & 3) >> 1];
        short8 bfr[4][2];

        #pragma unroll
        for (int q = 0; q < 4; ++q) {
            // ---- derived wait, then barrier (global visibility of staged units)
            if (q == 0) {
                asm volatile("s_waitcnt vmcnt(3)" ::: "memory");
                __builtin_amdgcn_s_barrier();
            } else if (q == 1) {
                if (pf) asm volatile("s_waitcnt vmcnt(4)" ::: "memory");
                else    asm volatile("s_waitcnt vmcnt(2)" ::: "memory");
                __builtin_amdgcn_s_barrier();
            } else if (q == 2) {
                if (pf) asm volatile("s_waitcnt vmcnt(4)" ::: "memory");
                else    asm volatile("s_waitcnt vmcnt(1)" ::: "memory");
                __builtin_amdgcn_s_barrier();
            } else if (!pf) {
                asm volatile("s_waitcnt vmcnt(0)" ::: "memory");
                __builtin_amdgcn_s_barrier();
            }
            __builtin_amdgcn_sched_barrier(0);

            // ---- ds-reads for this phase (B-frags once at q0; A-quad q)
            if (q == 0) {
                #pragma unroll
                for (int j = 0; j < 4; ++j) {
                    const int lr = (wn & 127) + j * 16 + fr;
                    const int sz = lr & 7;
                    bfr[j][0] = *(const short8*)&Bh[lr * 64 + (((0 + hi) ^ sz) << 3)];
                    bfr[j][1] = *(const short8*)&Bh[lr * 64 + (((4 + hi) ^ sz) << 3)];
                }
            }
            short8 af[2][2];
            #pragma unroll
            for (int ii = 0; ii < 2; ++ii) {
                const int lr = q * 32 + ii * 16 + fr;
                const int sz = lr & 7;
                af[ii][0] = *(const short8*)&Ah[lr * 64 + (((0 + hi) ^ sz) << 3)];
                af[ii][1] = *(const short8*)&Ah[lr * 64 + (((4 + hi) ^ sz) << 3)];
            }

            // ---- stage 2 units of tile kt+1 (FIFO: B0,B1 | B2,B3 | A0,A1 | A2,A3)
            if (pf) {
                if (q == 0)      { STAGE_B(buf ^ 1, k0n, 0); STAGE_B(buf ^ 1, k0n, 1); }
                else if (q == 1) { STAGE_B(buf ^ 1, k0n, 2); STAGE_B(buf ^ 1, k0n, 3); }
                else if (q == 2) { STAGE_A(buf ^ 1, k0n, 0); STAGE_A(buf ^ 1, k0n, 1); }
                else             { STAGE_A(buf ^ 1, k0n, 2); STAGE_A(buf ^ 1, k0n, 3); }
            }

            // ---- 16 MFMA (quadrant q)
            __builtin_amdgcn_s_setprio(1);
            #pragma unroll
            for (int ii = 0; ii < 2; ++ii)
                #pragma unroll
                for (int j = 0; j < 4; ++j) {
                    acc[q * 2 + ii][j] = __builtin_amdgcn_mfma_f32_16x16x32_bf16(
                        af[ii][0], bfr[j][0], acc[q * 2 + ii][j], 0, 0, 0);
                    acc[q * 2 + ii][j] = __builtin_amdgcn_mfma_f32_16x16x32_bf16(
                        af[ii][1], bfr[j][1], acc[q * 2 + ii][j], 0, 0, 0);
                }
            __builtin_amdgcn_s_setprio(0);
            __builtin_amdgcn_sched_barrier(0);
        }
        buf ^= 1;
    }

    // epilogue: C/D layout col=lane&15, row=(lane>>4)*4+reg (verified)
    const int crow = (lane >> 4) * 4, ccol = lane & 15;
    #pragma unroll
    for (int i = 0; i < 8; ++i)
        #pragma unroll
        for (int j = 0; j < 4; ++j) {
            CT* cp = C + (size_t)(m0 + wm + i * 16 + crow) * ldc + (n0 + wn + j * 16 + ccol);
            #pragma unroll
            for (int r = 0; r < 4; ++r) {
                if constexpr (sizeof(CT) == 2)
                    cp[(size_t)r * ldc] = bf16bits(acc[i][j][r]);
                else
                    cp[(size_t)r * ldc] = acc[i][j][r];
            }
        }
}

// ---------------- MFMA flash attention: swapped 32x32x16, in-register softmax,
// LDS-shared double-buffered K/V with counted vmcnt (verified r8) ----------------
__global__ __launch_bounds__(256, 2) void flash_mfma32(
    const unsigned short* __restrict__ Qb, int ldq,   // rope'd, pre-scaled
    const unsigned short* __restrict__ Kb, int ldk,   // rope'd
    const unsigned short* __restrict__ Vt,            // [B*KVH][HD][SLEN]
    unsigned short* __restrict__ Ob)                  // [MROWS][DMODEL]
{
    __shared__ unsigned short Ks[2][64 * 128];   // [kv 64][d 128], rows 256B, swz (row&15)<<4
    __shared__ unsigned short Vs[2][128 * 64];   // [d 128][kv 64], rows 128B, swz (row&7)<<4

    const int t = threadIdx.x;
    const int wid = t >> 6, lane = t & 63;
    const int qt = (int)gridDim.x - 1 - (int)blockIdx.x;   // heavy blocks first
    const int bh = blockIdx.y;
    const int b = bh >> 5, h = bh & 31, kvh = h >> 2;
    const int lq = lane & 31;
    const int hl = lane >> 5;
    const int qw0 = qt * 128 + wid * 32;
    const int qg = qw0 + lq;
    const size_t qrowg = (size_t)b * SLEN + qg;

    const unsigned short* Kg0 = Kb + (size_t)b * SLEN * ldk + kvh * HD;
    const unsigned short* Vg0 = Vt + (size_t)(b * KVHEADS + kvh) * HD * SLEN;

    auto STAGE = [&](int buf, int kt) {   // 8 GLDS16 per thread
        const unsigned short* Kg = Kg0 + (size_t)kt * 64 * ldk;
        #pragma unroll
        for (int i = 0; i < 4; ++i) {
            int row = i * 16 + (t >> 4);
            int colel = ((((t & 15) << 4) ^ ((row & 15) << 4)) >> 1);
            GLDS16(Kg + (size_t)row * ldk + colel, &Ks[buf][i * 2048 + wid * 512]);
        }
        const unsigned short* Vg = Vg0 + kt * 64;
        #pragma unroll
        for (int i = 0; i < 4; ++i) {
            int row = i * 32 + (t >> 3);
            int colel = ((((t & 7) << 4) ^ ((row & 7) << 4)) >> 1);
            GLDS16(Vg + (size_t)row * SLEN + colel, &Vs[buf][i * 2048 + wid * 512]);
        }
    };

    STAGE(0, 0);
    short8 qf[8];
    {
        const unsigned short* qp = Qb + qrowg * ldq + h * HD + hl * 8;
        #pragma unroll
        for (int dt = 0; dt < 8; ++dt)
            qf[dt] = *(const short8*)(qp + dt * 16);
    }

    f32x16 accO[4];
    #pragma unroll
    for (int db = 0; db < 4; ++db)
        #pragma unroll
        for (int r = 0; r < 16; ++r) accO[db][r] = 0.f;
    float m_i = -INFINITY, l_i = 0.f;

    const int ntmax = 2 * qt + 2;   // uniform across waves
    int p = 0;
    for (int kt = 0; kt < ntmax; ++kt) {
        if (kt + 1 < ntmax) {
            STAGE(p ^ 1, kt + 1);
            asm volatile("s_waitcnt vmcnt(8)" ::: "memory");
        } else {
            asm volatile("s_waitcnt vmcnt(0)" ::: "memory");
        }
        __builtin_amdgcn_s_barrier();
        __builtin_amdgcn_sched_barrier(0);

        const unsigned short* Kp = Ks[p];
        const unsigned short* Vp = Vs[p];

        // ---- QK^T: S^T[kv 64][q 32], 16 MFMA
        f32x16 sc[2];
        #pragma unroll
        for (int blk = 0; blk < 2; ++blk) {
            #pragma unroll
            for (int r = 0; r < 16; ++r) sc[blk][r] = 0.f;
            __builtin_amdgcn_s_setprio(1);
            #pragma unroll
            for (int dt = 0; dt < 8; ++dt) {
                int krow = blk * 32 + lq;
                int kb = krow * 256 + ((dt * 32 + hl * 16) ^ ((krow & 15) << 4));
                short8 kf = *(const short8*)(Kp + (kb >> 1));
                sc[blk] = __builtin_amdgcn_mfma_f32_32x32x16_bf16(kf, qf[dt], sc[blk], 0, 0, 0);
            }
            __builtin_amdgcn_s_setprio(0);
        }

        // ---- causal mask
        if (kt * 64 + 63 > qw0) {
            #pragma unroll
            for (int blk = 0; blk < 2; ++blk)
                #pragma unroll
                for (int r = 0; r < 16; ++r) {
                    int kv = kt * 64 + blk * 32 + (r & 3) + 8 * (r >> 2) + 4 * hl;
                    if (kv > qg) sc[blk][r] = -INFINITY;
                }
        }

        // ---- row max (in-lane + one cross-half swap)
        float pmax = sc[0][0];
        #pragma unroll
        for (int r = 1; r < 16; ++r) pmax = fmaxf(pmax, sc[0][r]);
        #pragma unroll
        for (int r = 0; r < 16; ++r) pmax = fmaxf(pmax, sc[1][r]);
        {
            i32x2 mr = __builtin_amdgcn_permlane32_swap(__float_as_int(pmax), __float_as_int(pmax), false, false);
            pmax = fmaxf(__int_as_float(mr.x), __int_as_float(mr.y));
        }

        // ---- defer-max rescale (THR=8 log2 -> P<=256)
        if (!__all(pmax <= m_i + 8.0f)) {
            float mn = fmaxf(m_i, pmax);
            float al = exp2f(m_i - mn);
            m_i = mn;
            l_i *= al;
            #pragma unroll
            for (int db = 0; db < 4; ++db)
                #pragma unroll
                for (int r = 0; r < 16; ++r) accO[db][r] *= al;
        }

        // ---- exp + row sum
        float rs = 0.f;
        #pragma unroll
        for (int blk = 0; blk < 2; ++blk)
            #pragma unroll
            for (int r = 0; r < 16; ++r) {
                float pv = exp2f(sc[blk][r] - m_i);
                sc[blk][r] = pv;
                rs += pv;
            }
        {
            i32x2 sr = __builtin_amdgcn_permlane32_swap(__float_as_int(rs), __float_as_int(rs), false, false);
            rs = __int_as_float(sr.x) + __int_as_float(sr.y);
        }
        l_i += rs;

        // ---- pack P -> PV B-fragments in registers (verified r7)
        short8 pf[4];
        #pragma unroll
        for (int blk = 0; blk < 2; ++blk) {
            unsigned c01 = cvtpk(sc[blk][0],  sc[blk][1]);
            unsigned c23 = cvtpk(sc[blk][2],  sc[blk][3]);
            unsigned c45 = cvtpk(sc[blk][4],  sc[blk][5]);
            unsigned c67 = cvtpk(sc[blk][6],  sc[blk][7]);
            i32x2 sA = __builtin_amdgcn_permlane32_swap((int)c01, (int)c45, false, false);
            i32x2 sB = __builtin_amdgcn_permlane32_swap((int)c23, (int)c67, false, false);
            u32x4 f0 = {(unsigned)sA.x, (unsigned)sB.x, (unsigned)sA.y, (unsigned)sB.y};
            pf[blk * 2] = *(short8*)&f0;
            unsigned c89 = cvtpk(sc[blk][8],  sc[blk][9]);
            unsigned cab = cvtpk(sc[blk][10], sc[blk][11]);
            unsigned ccd = cvtpk(sc[blk][12], sc[blk][13]);
            unsigned cef = cvtpk(sc[blk][14], sc[blk][15]);
            i32x2 sC = __builtin_amdgcn_permlane32_swap((int)c89, (int)ccd, false, false);
            i32x2 sD = __builtin_amdgcn_permlane32_swap((int)cab, (int)cef, false, false);
            u32x4 f1 = {(unsigned)sC.x, (unsigned)sD.x, (unsigned)sC.y, (unsigned)sD.y};
            pf[blk * 2 + 1] = *(short8*)&f1;
        }

        // ---- PV: O^T[d][q] accum, 16 MFMA
        #pragma unroll
        for (int db = 0; db < 4; ++db) {
            __builtin_amdgcn_s_setprio(1);
            #pragma unroll
            for (int ks = 0; ks < 4; ++ks) {
                int vrow = db * 32 + lq;
                int vb = vrow * 128 + ((ks * 32 + hl * 16) ^ ((vrow & 7) << 4));
                short8 vf = *(const short8*)(Vp + (vb >> 1));
                accO[db] = __builtin_amdgcn_mfma_f32_32x32x16_bf16(vf, pf[ks], accO[db], 0, 0, 0);
            }
            __builtin_amdgcn_s_setprio(0);
        }

        __builtin_amdgcn_sched_barrier(0);
        __builtin_amdgcn_s_barrier();
        p ^= 1;
    }

    // ---- epilogue
    float inv = 1.0f / l_i;
    unsigned short* orow = Ob + qrowg * DMODEL + h * HD;
    #pragma unroll
    for (int db = 0; db < 4; ++db)
        #pragma unroll
        for (int rq = 0; rq < 4; ++rq) {
            unsigned w0 = cvtpk(accO[db][rq * 4 + 0] * inv, accO[db][rq * 4 + 1] * inv);
            unsigned w1 = cvtpk(accO[db][rq * 4 + 2] * inv, accO[db][rq * 4 + 3] * inv);
            uint2 pkd; pkd.x = w0; pkd.y = w1;
            *(uint2*)(orow + db * 32 + rq * 8 + hl * 4) = pkd;
        }
}

extern "C" void kernel_launch(void* const* d_in, const int* in_sizes, int n_in,
                              void* d_out, int out_size, void* d_ws, size_t ws_size,
                              hipStream_t stream) {
    const float* hs  = (const float*)d_in[0];
    const int*   pos = (const int*)d_in[1];
    const float* wq  = (const float*)d_in[2];
    const float* wk  = (const float*)d_in[3];
    const float* wv  = (const float*)d_in[4];
    const float* wo  = (const float*)d_in[5];
    float* out = (float*)d_out;

    char* ws = (char*)d_ws;
    unsigned short* hs_bf   = (unsigned short*)(ws);                        // 32 MB
    unsigned short* wqkv_bf = (unsigned short*)(ws + ((size_t)32  << 20));  // 48 MB [6144][4096]
    unsigned short* wo_bf   = (unsigned short*)(ws + ((size_t)80  << 20));  // 32 MB
    unsigned short* qkv_bf  = (unsigned short*)(ws + ((size_t)112 << 20));  // 48 MB [4096][6144]
    unsigned short* Vtb     = (unsigned short*)(ws + ((size_t)160 << 20));  // 8 MB
    unsigned short* Obf     = (unsigned short*)(ws + ((size_t)168 << 20));  // 32 MB
    float*          cosT    = (float*)(ws + ((size_t)200 << 20));           // 512 KB
    float*          sinT    = (float*)(ws + ((size_t)200 << 20) + (size_t)SLEN * 64 * 4);
    // total ~201 MB

    const long nHS = (long)MROWS * DMODEL;
    const long nWQ = (long)DMODEL * DMODEL;
    const long nWK = (long)KVDIM * DMODEL;

    rope_table_k<<<SLEN, 64, 0, stream>>>(pos, cosT, sinT);

    cast_k<<<nHS / 4 / 256, 256, 0, stream>>>(hs, hs_bf, nHS);
    cast_k<<<nWQ / 4 / 256, 256, 0, stream>>>(wq, wqkv_bf, nWQ);
    cast_k<<<nWK / 4 / 256, 256, 0, stream>>>(wk, wqkv_bf + (size_t)DMODEL * DMODEL, nWK);
    cast_k<<<nWK / 4 / 256, 256, 0, stream>>>(wv, wqkv_bf + (size_t)(DMODEL + KVDIM) * DMODEL, nWK);
    cast_k<<<nWQ / 4 / 256, 256, 0, stream>>>(wo, wo_bf, nWQ);

    // fused QKV projection: [4096][6144] bf16
    gemm256<unsigned short><<<dim3(NQKV/256, MROWS/256), 512, 0, stream>>>(
        hs_bf, DMODEL, wqkv_bf, DMODEL, qkv_bf, NQKV, MROWS, NQKV, DMODEL);

    // Q gets (1/sqrt(128)) * log2(e) folded in; K unscaled
    const float qmul = 0.088388347648318447f * 1.4426950408889634f;
    rope_bf_k<<<(MROWS * NHEADS  * 64) / 256, 256, 0, stream>>>(qkv_bf,          cosT, sinT, NHEADS,  NQKV, qmul);
    rope_bf_k<<<(MROWS * KVHEADS * 64) / 256, 256, 0, stream>>>(qkv_bf + DMODEL, cosT, sinT, KVHEADS, NQKV, 1.0f);
    vtrans_k<<<dim3(SLEN/64, BATCH*KVHEADS), 256, 0, stream>>>(qkv_bf + DMODEL + KVDIM, NQKV, Vtb);

    flash_mfma32<<<dim3(SLEN/128, BATCH*NHEADS), 256, 0, stream>>>(
        qkv_bf, NQKV, qkv_bf + DMODEL, NQKV, Vtb, Obf);

    gemm256<float><<<dim3(DMODEL/256, MROWS/256), 512, 0, stream>>>(
        Obf, DMODEL, wo_bf, DMODEL, out, DMODEL, MROWS, DMODEL, DMODEL);
}

// Round 13
// 624.068 us; speedup vs baseline: 1.0433x; 1.0021x over previous
//
#include <hip/hip_runtime.h>
#include <hip/hip_bf16.h>
#include <math.h>

typedef __attribute__((ext_vector_type(8))) short short8;
typedef __attribute__((ext_vector_type(4))) float f32x4;
typedef __attribute__((ext_vector_type(16))) float f32x16;
typedef __attribute__((ext_vector_type(4))) unsigned int u32x4;
typedef __attribute__((ext_vector_type(2))) int i32x2;

#define BATCH   2
#define SLEN    2048
#define DMODEL  4096
#define NHEADS  32
#define KVHEADS 8
#define HD      128
#define KVDIM   (KVHEADS*HD)   // 1024
#define MROWS   (BATCH*SLEN)   // 4096
#define NQKV    (DMODEL + 2*KVDIM)   // 6144

// async global->LDS, 16B per lane, dest = wave-uniform base + lane*16
#define GLDS16(gp, lp) __builtin_amdgcn_global_load_lds( \
    (const __attribute__((address_space(1))) void*)(gp), \
    (__attribute__((address_space(3))) void*)(lp), 16, 0, 0)

static __device__ __forceinline__ unsigned short bf16bits(float x) {
    __hip_bfloat16 h = __float2bfloat16(x);
    return *(unsigned short*)&h;
}
static __device__ __forceinline__ float bf2f(unsigned short u) {
    __hip_bfloat16 h = *(__hip_bfloat16*)&u;
    return __bfloat162float(h);
}
// v_cvt_pk_bf16_f32: lo=src0, hi=src1 (no builtin on gfx950)
static __device__ __forceinline__ unsigned cvtpk(float a, float b) {
    unsigned r;
    asm("v_cvt_pk_bf16_f32 %0, %1, %2" : "=v"(r) : "v"(a), "v"(b));
    return r;
}

// ---------------- fp32 -> bf16 cast ----------------
__global__ __launch_bounds__(256) void cast_k(const float* __restrict__ in,
                                              unsigned short* __restrict__ out, long n) {
    long i = ((long)blockIdx.x * 256 + threadIdx.x) * 4;
    if (i >= n) return;
    float4 v = *(const float4*)(in + i);
    union { unsigned short h[4]; uint2 u; } c;
    c.h[0] = bf16bits(v.x); c.h[1] = bf16bits(v.y);
    c.h[2] = bf16bits(v.z); c.h[3] = bf16bits(v.w);
    *(uint2*)(out + i) = c.u;
}

// ---------------- RoPE tables ----------------
__global__ void rope_table_k(const int* __restrict__ pos,
                             float* __restrict__ cosT, float* __restrict__ sinT) {
    int s = blockIdx.x;
    int d = threadIdx.x;
    float p = (float)pos[s];
    float inv = powf(10000.0f, -(float)(2 * d) / 128.0f);
    float ang = p * inv;
    cosT[s * 64 + d] = cosf(ang);
    sinT[s * 64 + d] = sinf(ang);
}

// ---------------- RoPE apply in-place on bf16, row stride ld ----------------
__global__ void rope_bf_k(unsigned short* __restrict__ x,
                          const float* __restrict__ cosT, const float* __restrict__ sinT,
                          int nh, int ld, float mul) {
    int idx = blockIdx.x * 256 + threadIdx.x;
    int d = idx & 63;
    int rest = idx >> 6;
    int h = rest % nh;
    int row = rest / nh;
    int s = row & (SLEN - 1);
    float c  = cosT[s * 64 + d] * mul;
    float sn = sinT[s * 64 + d] * mul;
    unsigned short* base = x + (size_t)row * ld + h * HD;
    float x1 = bf2f(base[d]), x2 = bf2f(base[d + 64]);
    base[d]      = bf16bits(x1 * c - x2 * sn);
    base[d + 64] = bf16bits(x2 * c + x1 * sn);
}

// ---------------- V transpose: bf16 [M][ldv] -> bf16 Vt[b*KVH+kvh][d=128][s=2048] ----------------
__global__ __launch_bounds__(256) void vtrans_k(const unsigned short* __restrict__ V, int ldv,
                                                unsigned short* __restrict__ Vt) {
    __shared__ unsigned short L[64][144];
    const int t = threadIdx.x;
    const int s0 = blockIdx.x * 64;
    const int bk = blockIdx.y;              // b*KVH + kvh
    const int b = bk >> 3, kvh = bk & 7;
    #pragma unroll
    for (int j = 0; j < 4; ++j) {
        int idx = t + j * 256;
        int row = idx >> 4;
        int c8  = (idx & 15) * 8;
        *(short8*)&L[row][c8] =
            *(const short8*)(V + ((size_t)b * SLEN + s0 + row) * ldv + kvh * HD + c8);
    }
    __syncthreads();
    {
        int d  = t >> 1;
        int sh = (t & 1) * 32;
        unsigned short tmp[32];
        #pragma unroll
        for (int j = 0; j < 32; ++j) tmp[j] = L[sh + j][d];
        unsigned short* dst = Vt + ((size_t)bk * HD + d) * SLEN + s0 + sh;
        #pragma unroll
        for (int j = 0; j < 4; ++j)
            *(short8*)(dst + j * 8) = *(const short8*)(tmp + j * 8);
    }
}

// ---------------- 256x256 bf16 MFMA GEMM-NT, BK=64, 8 waves, staggered-unit staging ----------------
// Unit-granularity WAR: tile T's B region is dead after T.q0 (B frags register-cached),
// A-unit q dead after phase q. Stage schedule (2 loads/thread/phase):
//   T.q0: A2A3(T+1) -> buf^1      T.q1: B0B1(T+2) -> buf
//   T.q2: B2B3(T+2) -> buf        T.q3: A0A1(T+2) -> buf
// FIFO waits (wait BEFORE this phase's stages, then barrier):
//   T.q0: vmcnt(8)  [through A0A1(T), issued 5 phases ago]   (tail: 2)
//   T.q2: vmcnt(10) [through A2A3(T), issued 6 phases ago]   (tail: 8 / 0)
// 8-10 loads permanently in flight; issue-to-consume 5-7 phases. 1 barrier/phase.
// LDS [128][64] halves, slot^=(row&7) swizzle (conflict-free, verified r8+).
// Rect per-XCD chunking (r11, FETCH 354->176MB).
template<typename CT>
__global__ __launch_bounds__(512, 1) void gemm256(
    const unsigned short* __restrict__ A, int lda,
    const unsigned short* __restrict__ W, int ldw,
    CT* __restrict__ C, int ldc,
    int M, int N, int K)
{
    __shared__ unsigned short Asl[2][2][128 * 64];   // [buf][half][row*64 + col]
    __shared__ unsigned short Bsl[2][2][128 * 64];

    const int t = threadIdx.x;           // 0..511
    const int w = t >> 6, lane = t & 63;

    // rectangular per-XCD chunking
    const int gx = gridDim.x;
    const int nwg = gx * gridDim.y;
    const int chunk = nwg >> 3;
    const int orig = blockIdx.y * gx + blockIdx.x;
    const int xcd = orig & 7, idx = orig >> 3;
    const int rn = chunk >> 3;
    const int nrx = gx / rn;
    const int rx = xcd % nrx, ry = xcd / nrx;
    const int iy = idx / rn, ix = idx % rn;
    const int m0 = (ry * 8 + iy) * 256;
    const int n0 = (rx * rn + ix) * 256;

    const int wm = (w >> 2) * 128;
    const int wn = (w & 3) * 64;
    const int fr = lane & 15, hi = lane >> 4;

    f32x4 acc[8][4];
    #pragma unroll
    for (int i = 0; i < 8; ++i)
        #pragma unroll
        for (int j = 0; j < 4; ++j)
            acc[i][j] = (f32x4){0.f, 0.f, 0.f, 0.f};

    const int sl = t & 7;
    const int srw = (t >> 3) & 7;        // swizzle row bits
    const int wv512 = w * 512;

    // stage unit helpers: 1 GLDS16 per thread each
    auto STAGE_B = [&](int bufn, int k0, int u) {
        const int row = u * 64 + (t >> 3);                       // N-row 0..255
        const int scol = k0 + ((sl ^ srw) << 3);
        GLDS16(W + (size_t)(n0 + row) * ldw + scol,
               &Bsl[bufn][u >> 1][(u & 1) * 4096 + wv512]);
    };
    auto STAGE_A = [&](int bufn, int k0, int u) {
        const int half = w >> 2;
        const int row = half * 128 + u * 32 + ((t & 255) >> 3);  // M-row
        const int scol = k0 + ((sl ^ srw) << 3);
        GLDS16(A + (size_t)(m0 + row) * lda + scol,
               &Asl[bufn][half][u * 2048 + (w & 3) * 512]);
    };

    const int NT = K >> 6;

    // ---- prologue: virtual phases in exact FIFO order
    // (-2).q1..q3: T0 B0B1, B2B3, A0A1 ; (-1).q0: T0 A2A3 ; (-1).q1..q3: T1 B0B1, B2B3, A0A1
    STAGE_B(0, 0, 0); STAGE_B(0, 0, 1);
    STAGE_B(0, 0, 2); STAGE_B(0, 0, 3);
    STAGE_A(0, 0, 0); STAGE_A(0, 0, 1);
    STAGE_A(0, 0, 2); STAGE_A(0, 0, 3);
    if (NT > 1) {
        STAGE_B(1, 64, 0); STAGE_B(1, 64, 1);
        STAGE_B(1, 64, 2); STAGE_B(1, 64, 3);
        STAGE_A(1, 64, 0); STAGE_A(1, 64, 1);
    }

    int buf = 0;
    for (int kt = 0; kt < NT; ++kt) {
        const bool p1 = (kt + 1 < NT);
        const bool p2 = (kt + 2 < NT);
        const unsigned short* Ah = Asl[buf][w >> 2];
        const unsigned short* Bh = Bsl[buf][(w & 3) >> 1];
        const int k1 = (kt + 1) << 6;
        const int k2 = (kt + 2) << 6;
        const int b1 = buf ^ 1;
        short8 bfr[4][2];

        #pragma unroll
        for (int q = 0; q < 4; ++q) {
            // ---- derived wait (before this phase's stages), then barrier
            if (q == 0) {
                if (p1) asm volatile("s_waitcnt vmcnt(8)" ::: "memory");
                else    asm volatile("s_waitcnt vmcnt(2)" ::: "memory");
            } else if (q == 2) {
                if (p2)      asm volatile("s_waitcnt vmcnt(10)" ::: "memory");
                else if (p1) asm volatile("s_waitcnt vmcnt(8)" ::: "memory");
                else         asm volatile("s_waitcnt vmcnt(0)" ::: "memory");
            }
            __builtin_amdgcn_sched_barrier(0);
            __builtin_amdgcn_s_barrier();
            __builtin_amdgcn_sched_barrier(0);

            // ---- ds-reads for this phase (B-frags once at q0; A-quad q)
            if (q == 0) {
                #pragma unroll
                for (int j = 0; j < 4; ++j) {
                    const int lr = (wn & 127) + j * 16 + fr;
                    const int sz = lr & 7;
                    bfr[j][0] = *(const short8*)&Bh[lr * 64 + (((0 + hi) ^ sz) << 3)];
                    bfr[j][1] = *(const short8*)&Bh[lr * 64 + (((4 + hi) ^ sz) << 3)];
                }
            }
            short8 af[2][2];
            #pragma unroll
            for (int ii = 0; ii < 2; ++ii) {
                const int lr = q * 32 + ii * 16 + fr;
                const int sz = lr & 7;
                af[ii][0] = *(const short8*)&Ah[lr * 64 + (((0 + hi) ^ sz) << 3)];
                af[ii][1] = *(const short8*)&Ah[lr * 64 + (((4 + hi) ^ sz) << 3)];
            }

            // ---- staggered stage (regions freed by previous phases of this tile)
            if (q == 0)      { if (p1) { STAGE_A(b1, k1, 2); STAGE_A(b1, k1, 3); } }
            else if (q == 1) { if (p2) { STAGE_B(buf, k2, 0); STAGE_B(buf, k2, 1); } }
            else if (q == 2) { if (p2) { STAGE_B(buf, k2, 2); STAGE_B(buf, k2, 3); } }
            else             { if (p2) { STAGE_A(buf, k2, 0); STAGE_A(buf, k2, 1); } }

            // ---- 16 MFMA (quadrant q)
            __builtin_amdgcn_s_setprio(1);
            #pragma unroll
            for (int ii = 0; ii < 2; ++ii)
                #pragma unroll
                for (int j = 0; j < 4; ++j) {
                    acc[q * 2 + ii][j] = __builtin_amdgcn_mfma_f32_16x16x32_bf16(
                        af[ii][0], bfr[j][0], acc[q * 2 + ii][j], 0, 0, 0);
                    acc[q * 2 + ii][j] = __builtin_amdgcn_mfma_f32_16x16x32_bf16(
                        af[ii][1], bfr[j][1], acc[q * 2 + ii][j], 0, 0, 0);
                }
            __builtin_amdgcn_s_setprio(0);
            __builtin_amdgcn_sched_barrier(0);
        }
        buf ^= 1;
    }

    // epilogue: C/D layout col=lane&15, row=(lane>>4)*4+reg (verified)
    const int crow = (lane >> 4) * 4, ccol = lane & 15;
    #pragma unroll
    for (int i = 0; i < 8; ++i)
        #pragma unroll
        for (int j = 0; j < 4; ++j) {
            CT* cp = C + (size_t)(m0 + wm + i * 16 + crow) * ldc + (n0 + wn + j * 16 + ccol);
            #pragma unroll
            for (int r = 0; r < 4; ++r) {
                if constexpr (sizeof(CT) == 2)
                    cp[(size_t)r * ldc] = bf16bits(acc[i][j][r]);
                else
                    cp[(size_t)r * ldc] = acc[i][j][r];
            }
        }
}

// ---------------- MFMA flash attention: swapped 32x32x16, in-register softmax,
// LDS-shared double-buffered K/V with counted vmcnt (verified r8) ----------------
__global__ __launch_bounds__(256, 2) void flash_mfma32(
    const unsigned short* __restrict__ Qb, int ldq,   // rope'd, pre-scaled
    const unsigned short* __restrict__ Kb, int ldk,   // rope'd
    const unsigned short* __restrict__ Vt,            // [B*KVH][HD][SLEN]
    unsigned short* __restrict__ Ob)                  // [MROWS][DMODEL]
{
    __shared__ unsigned short Ks[2][64 * 128];   // [kv 64][d 128], rows 256B, swz (row&15)<<4
    __shared__ unsigned short Vs[2][128 * 64];   // [d 128][kv 64], rows 128B, swz (row&7)<<4

    const int t = threadIdx.x;
    const int wid = t >> 6, lane = t & 63;
    const int qt = (int)gridDim.x - 1 - (int)blockIdx.x;   // heavy blocks first
    const int bh = blockIdx.y;
    const int b = bh >> 5, h = bh & 31, kvh = h >> 2;
    const int lq = lane & 31;
    const int hl = lane >> 5;
    const int qw0 = qt * 128 + wid * 32;
    const int qg = qw0 + lq;
    const size_t qrowg = (size_t)b * SLEN + qg;

    const unsigned short* Kg0 = Kb + (size_t)b * SLEN * ldk + kvh * HD;
    const unsigned short* Vg0 = Vt + (size_t)(b * KVHEADS + kvh) * HD * SLEN;

    auto STAGE = [&](int buf, int kt) {   // 8 GLDS16 per thread
        const unsigned short* Kg = Kg0 + (size_t)kt * 64 * ldk;
        #pragma unroll
        for (int i = 0; i < 4; ++i) {
            int row = i * 16 + (t >> 4);
            int colel = ((((t & 15) << 4) ^ ((row & 15) << 4)) >> 1);
            GLDS16(Kg + (size_t)row * ldk + colel, &Ks[buf][i * 2048 + wid * 512]);
        }
        const unsigned short* Vg = Vg0 + kt * 64;
        #pragma unroll
        for (int i = 0; i < 4; ++i) {
            int row = i * 32 + (t >> 3);
            int colel = ((((t & 7) << 4) ^ ((row & 7) << 4)) >> 1);
            GLDS16(Vg + (size_t)row * SLEN + colel, &Vs[buf][i * 2048 + wid * 512]);
        }
    };

    STAGE(0, 0);
    short8 qf[8];
    {
        const unsigned short* qp = Qb + qrowg * ldq + h * HD + hl * 8;
        #pragma unroll
        for (int dt = 0; dt < 8; ++dt)
            qf[dt] = *(const short8*)(qp + dt * 16);
    }

    f32x16 accO[4];
    #pragma unroll
    for (int db = 0; db < 4; ++db)
        #pragma unroll
        for (int r = 0; r < 16; ++r) accO[db][r] = 0.f;
    float m_i = -INFINITY, l_i = 0.f;

    const int ntmax = 2 * qt + 2;   // uniform across waves
    int p = 0;
    for (int kt = 0; kt < ntmax; ++kt) {
        if (kt + 1 < ntmax) {
            STAGE(p ^ 1, kt + 1);
            asm volatile("s_waitcnt vmcnt(8)" ::: "memory");
        } else {
            asm volatile("s_waitcnt vmcnt(0)" ::: "memory");
        }
        __builtin_amdgcn_s_barrier();
        __builtin_amdgcn_sched_barrier(0);

        const unsigned short* Kp = Ks[p];
        const unsigned short* Vp = Vs[p];

        // ---- QK^T: S^T[kv 64][q 32], 16 MFMA
        f32x16 sc[2];
        #pragma unroll
        for (int blk = 0; blk < 2; ++blk) {
            #pragma unroll
            for (int r = 0; r < 16; ++r) sc[blk][r] = 0.f;
            __builtin_amdgcn_s_setprio(1);
            #pragma unroll
            for (int dt = 0; dt < 8; ++dt) {
                int krow = blk * 32 + lq;
                int kb = krow * 256 + ((dt * 32 + hl * 16) ^ ((krow & 15) << 4));
                short8 kf = *(const short8*)(Kp + (kb >> 1));
                sc[blk] = __builtin_amdgcn_mfma_f32_32x32x16_bf16(kf, qf[dt], sc[blk], 0, 0, 0);
            }
            __builtin_amdgcn_s_setprio(0);
        }

        // ---- causal mask
        if (kt * 64 + 63 > qw0) {
            #pragma unroll
            for (int blk = 0; blk < 2; ++blk)
                #pragma unroll
                for (int r = 0; r < 16; ++r) {
                    int kv = kt * 64 + blk * 32 + (r & 3) + 8 * (r >> 2) + 4 * hl;
                    if (kv > qg) sc[blk][r] = -INFINITY;
                }
        }

        // ---- row max (in-lane + one cross-half swap)
        float pmax = sc[0][0];
        #pragma unroll
        for (int r = 1; r < 16; ++r) pmax = fmaxf(pmax, sc[0][r]);
        #pragma unroll
        for (int r = 0; r < 16; ++r) pmax = fmaxf(pmax, sc[1][r]);
        {
            i32x2 mr = __builtin_amdgcn_permlane32_swap(__float_as_int(pmax), __float_as_int(pmax), false, false);
            pmax = fmaxf(__int_as_float(mr.x), __int_as_float(mr.y));
        }

        // ---- defer-max rescale (THR=8 log2 -> P<=256)
        if (!__all(pmax <= m_i + 8.0f)) {
            float mn = fmaxf(m_i, pmax);
            float al = exp2f(m_i - mn);
            m_i = mn;
            l_i *= al;
            #pragma unroll
            for (int db = 0; db < 4; ++db)
                #pragma unroll
                for (int r = 0; r < 16; ++r) accO[db][r] *= al;
        }

        // ---- exp + row sum
        float rs = 0.f;
        #pragma unroll
        for (int blk = 0; blk < 2; ++blk)
            #pragma unroll
            for (int r = 0; r < 16; ++r) {
                float pv = exp2f(sc[blk][r] - m_i);
                sc[blk][r] = pv;
                rs += pv;
            }
        {
            i32x2 sr = __builtin_amdgcn_permlane32_swap(__float_as_int(rs), __float_as_int(rs), false, false);
            rs = __int_as_float(sr.x) + __int_as_float(sr.y);
        }
        l_i += rs;

        // ---- pack P -> PV B-fragments in registers (verified r7)
        short8 pf[4];
        #pragma unroll
        for (int blk = 0; blk < 2; ++blk) {
            unsigned c01 = cvtpk(sc[blk][0],  sc[blk][1]);
            unsigned c23 = cvtpk(sc[blk][2],  sc[blk][3]);
            unsigned c45 = cvtpk(sc[blk][4],  sc[blk][5]);
            unsigned c67 = cvtpk(sc[blk][6],  sc[blk][7]);
            i32x2 sA = __builtin_amdgcn_permlane32_swap((int)c01, (int)c45, false, false);
            i32x2 sB = __builtin_amdgcn_permlane32_swap((int)c23, (int)c67, false, false);
            u32x4 f0 = {(unsigned)sA.x, (unsigned)sB.x, (unsigned)sA.y, (unsigned)sB.y};
            pf[blk * 2] = *(short8*)&f0;
            unsigned c89 = cvtpk(sc[blk][8],  sc[blk][9]);
            unsigned cab = cvtpk(sc[blk][10], sc[blk][11]);
            unsigned ccd = cvtpk(sc[blk][12], sc[blk][13]);
            unsigned cef = cvtpk(sc[blk][14], sc[blk][15]);
            i32x2 sC = __builtin_amdgcn_permlane32_swap((int)c89, (int)ccd, false, false);
            i32x2 sD = __builtin_amdgcn_permlane32_swap((int)cab, (int)cef, false, false);
            u32x4 f1 = {(unsigned)sC.x, (unsigned)sD.x, (unsigned)sC.y, (unsigned)sD.y};
            pf[blk * 2 + 1] = *(short8*)&f1;
        }

        // ---- PV: O^T[d][q] accum, 16 MFMA
        #pragma unroll
        for (int db = 0; db < 4; ++db) {
            __builtin_amdgcn_s_setprio(1);
            #pragma unroll
            for (int ks = 0; ks < 4; ++ks) {
                int vrow = db * 32 + lq;
                int vb = vrow * 128 + ((ks * 32 + hl * 16) ^ ((vrow & 7) << 4));
                short8 vf = *(const short8*)(Vp + (vb >> 1));
                accO[db] = __builtin_amdgcn_mfma_f32_32x32x16_bf16(vf, pf[ks], accO[db], 0, 0, 0);
            }
            __builtin_amdgcn_s_setprio(0);
        }

        __builtin_amdgcn_sched_barrier(0);
        __builtin_amdgcn_s_barrier();
        p ^= 1;
    }

    // ---- epilogue
    float inv = 1.0f / l_i;
    unsigned short* orow = Ob + qrowg * DMODEL + h * HD;
    #pragma unroll
    for (int db = 0; db < 4; ++db)
        #pragma unroll
        for (int rq = 0; rq < 4; ++rq) {
            unsigned w0 = cvtpk(accO[db][rq * 4 + 0] * inv, accO[db][rq * 4 + 1] * inv);
            unsigned w1 = cvtpk(accO[db][rq * 4 + 2] * inv, accO[db][rq * 4 + 3] * inv);
            uint2 pkd; pkd.x = w0; pkd.y = w1;
            *(uint2*)(orow + db * 32 + rq * 8 + hl * 4) = pkd;
        }
}

extern "C" void kernel_launch(void* const* d_in, const int* in_sizes, int n_in,
                              void* d_out, int out_size, void* d_ws, size_t ws_size,
                              hipStream_t stream) {
    const float* hs  = (const float*)d_in[0];
    const int*   pos = (const int*)d_in[1];
    const float* wq  = (const float*)d_in[2];
    const float* wk  = (const float*)d_in[3];
    const float* wv  = (const float*)d_in[4];
    const float* wo  = (const float*)d_in[5];
    float* out = (float*)d_out;

    char* ws = (char*)d_ws;
    unsigned short* hs_bf   = (unsigned short*)(ws);                        // 32 MB
    unsigned short* wqkv_bf = (unsigned short*)(ws + ((size_t)32  << 20));  // 48 MB [6144][4096]
    unsigned short* wo_bf   = (unsigned short*)(ws + ((size_t)80  << 20));  // 32 MB
    unsigned short* qkv_bf  = (unsigned short*)(ws + ((size_t)112 << 20));  // 48 MB [4096][6144]
    unsigned short* Vtb     = (unsigned short*)(ws + ((size_t)160 << 20));  // 8 MB
    unsigned short* Obf     = (unsigned short*)(ws + ((size_t)168 << 20));  // 32 MB
    float*          cosT    = (float*)(ws + ((size_t)200 << 20));           // 512 KB
    float*          sinT    = (float*)(ws + ((size_t)200 << 20) + (size_t)SLEN * 64 * 4);
    // total ~201 MB

    const long nHS = (long)MROWS * DMODEL;
    const long nWQ = (long)DMODEL * DMODEL;
    const long nWK = (long)KVDIM * DMODEL;

    rope_table_k<<<SLEN, 64, 0, stream>>>(pos, cosT, sinT);

    cast_k<<<nHS / 4 / 256, 256, 0, stream>>>(hs, hs_bf, nHS);
    cast_k<<<nWQ / 4 / 256, 256, 0, stream>>>(wq, wqkv_bf, nWQ);
    cast_k<<<nWK / 4 / 256, 256, 0, stream>>>(wk, wqkv_bf + (size_t)DMODEL * DMODEL, nWK);
    cast_k<<<nWK / 4 / 256, 256, 0, stream>>>(wv, wqkv_bf + (size_t)(DMODEL + KVDIM) * DMODEL, nWK);
    cast_k<<<nWQ / 4 / 256, 256, 0, stream>>>(wo, wo_bf, nWQ);

    // fused QKV projection: [4096][6144] bf16
    gemm256<unsigned short><<<dim3(NQKV/256, MROWS/256), 512, 0, stream>>>(
        hs_bf, DMODEL, wqkv_bf, DMODEL, qkv_bf, NQKV, MROWS, NQKV, DMODEL);

    // Q gets (1/sqrt(128)) * log2(e) folded in; K unscaled
    const float qmul = 0.088388347648318447f * 1.4426950408889634f;
    rope_bf_k<<<(MROWS * NHEADS  * 64) / 256, 256, 0, stream>>>(qkv_bf,          cosT, sinT, NHEADS,  NQKV, qmul);
    rope_bf_k<<<(MROWS * KVHEADS * 64) / 256, 256, 0, stream>>>(qkv_bf + DMODEL, cosT, sinT, KVHEADS, NQKV, 1.0f);
    vtrans_k<<<dim3(SLEN/64, BATCH*KVHEADS), 256, 0, stream>>>(qkv_bf + DMODEL + KVDIM, NQKV, Vtb);

    flash_mfma32<<<dim3(SLEN/128, BATCH*NHEADS), 256, 0, stream>>>(
        qkv_bf, NQKV, qkv_bf + DMODEL, NQKV, Vtb, Obf);

    gemm256<float><<<dim3(DMODEL/256, MROWS/256), 512, 0, stream>>>(
        Obf, DMODEL, wo_bf, DMODEL, out, DMODEL, MROWS, DMODEL, DMODEL);
}

// Round 14
// 595.041 us; speedup vs baseline: 1.0942x; 1.0488x over previous
//
#include <hip/hip_runtime.h>
#include <hip/hip_bf16.h>
#include <math.h>

typedef __attribute__((ext_vector_type(8))) short short8;
typedef __attribute__((ext_vector_type(4))) float f32x4;
typedef __attribute__((ext_vector_type(16))) float f32x16;
typedef __attribute__((ext_vector_type(4))) unsigned int u32x4;
typedef __attribute__((ext_vector_type(2))) int i32x2;

#define BATCH   2
#define SLEN    2048
#define DMODEL  4096
#define NHEADS  32
#define KVHEADS 8
#define HD      128
#define KVDIM   (KVHEADS*HD)   // 1024
#define MROWS   (BATCH*SLEN)   // 4096
#define NQKV    (DMODEL + 2*KVDIM)   // 6144

// async global->LDS, 16B per lane, dest = wave-uniform base + lane*16
#define GLDS16(gp, lp) __builtin_amdgcn_global_load_lds( \
    (const __attribute__((address_space(1))) void*)(gp), \
    (__attribute__((address_space(3))) void*)(lp), 16, 0, 0)

static __device__ __forceinline__ unsigned short bf16bits(float x) {
    __hip_bfloat16 h = __float2bfloat16(x);
    return *(unsigned short*)&h;
}
static __device__ __forceinline__ float bf2f(unsigned short u) {
    __hip_bfloat16 h = *(__hip_bfloat16*)&u;
    return __bfloat162float(h);
}
// v_cvt_pk_bf16_f32: lo=src0, hi=src1 (no builtin on gfx950)
static __device__ __forceinline__ unsigned cvtpk(float a, float b) {
    unsigned r;
    asm("v_cvt_pk_bf16_f32 %0, %1, %2" : "=v"(r) : "v"(a), "v"(b));
    return r;
}

// ---------------- fp32 -> bf16 cast ----------------
__global__ __launch_bounds__(256) void cast_k(const float* __restrict__ in,
                                              unsigned short* __restrict__ out, long n) {
    long i = ((long)blockIdx.x * 256 + threadIdx.x) * 4;
    if (i >= n) return;
    float4 v = *(const float4*)(in + i);
    union { unsigned short h[4]; uint2 u; } c;
    c.h[0] = bf16bits(v.x); c.h[1] = bf16bits(v.y);
    c.h[2] = bf16bits(v.z); c.h[3] = bf16bits(v.w);
    *(uint2*)(out + i) = c.u;
}

// ---------------- RoPE tables ----------------
__global__ void rope_table_k(const int* __restrict__ pos,
                             float* __restrict__ cosT, float* __restrict__ sinT) {
    int s = blockIdx.x;
    int d = threadIdx.x;
    float p = (float)pos[s];
    float inv = powf(10000.0f, -(float)(2 * d) / 128.0f);
    float ang = p * inv;
    cosT[s * 64 + d] = cosf(ang);
    sinT[s * 64 + d] = sinf(ang);
}

// ---------------- RoPE apply in-place on bf16, row stride ld ----------------
__global__ void rope_bf_k(unsigned short* __restrict__ x,
                          const float* __restrict__ cosT, const float* __restrict__ sinT,
                          int nh, int ld, float mul) {
    int idx = blockIdx.x * 256 + threadIdx.x;
    int d = idx & 63;
    int rest = idx >> 6;
    int h = rest % nh;
    int row = rest / nh;
    int s = row & (SLEN - 1);
    float c  = cosT[s * 64 + d] * mul;
    float sn = sinT[s * 64 + d] * mul;
    unsigned short* base = x + (size_t)row * ld + h * HD;
    float x1 = bf2f(base[d]), x2 = bf2f(base[d + 64]);
    base[d]      = bf16bits(x1 * c - x2 * sn);
    base[d + 64] = bf16bits(x2 * c + x1 * sn);
}

// ---------------- V transpose: bf16 [M][ldv] -> bf16 Vt[b*KVH+kvh][d=128][s=2048] ----------------
__global__ __launch_bounds__(256) void vtrans_k(const unsigned short* __restrict__ V, int ldv,
                                                unsigned short* __restrict__ Vt) {
    __shared__ unsigned short L[64][144];
    const int t = threadIdx.x;
    const int s0 = blockIdx.x * 64;
    const int bk = blockIdx.y;              // b*KVH + kvh
    const int b = bk >> 3, kvh = bk & 7;
    #pragma unroll
    for (int j = 0; j < 4; ++j) {
        int idx = t + j * 256;
        int row = idx >> 4;
        int c8  = (idx & 15) * 8;
        *(short8*)&L[row][c8] =
            *(const short8*)(V + ((size_t)b * SLEN + s0 + row) * ldv + kvh * HD + c8);
    }
    __syncthreads();
    {
        int d  = t >> 1;
        int sh = (t & 1) * 32;
        unsigned short tmp[32];
        #pragma unroll
        for (int j = 0; j < 32; ++j) tmp[j] = L[sh + j][d];
        unsigned short* dst = Vt + ((size_t)bk * HD + d) * SLEN + s0 + sh;
        #pragma unroll
        for (int j = 0; j < 4; ++j)
            *(short8*)(dst + j * 8) = *(const short8*)(tmp + j * 8);
    }
}

// ---------------- 256x256 bf16 MFMA GEMM-NT, BK=64, 8 waves ----------------
// 4 phases/tile: reads+stages BEFORE barrier (latency hides in barrier wait), MFMA after,
// counted waits after MFMA. B-fragment PING-PONG: tile T's q2/q3 read tile T+1's B-frags
// from the other LDS buffer into bn regs -> q0 needs only 4 A-reads (phases 4/4/8/8).
// Stagger (2 loads/thread/phase): q0: A2A3(T+1)->buf^1; q1: B0B1(T+2)->buf;
// q2: B2B3(T+2)->buf; q3: A0A1(T+2)->buf. Derived FIFO waits (after MFMA, before bar):
//   q1-end: vmcnt(6) [B(T+1)+A2A3(T) landed]  tail: 4 / 0
//   q3-end: vmcnt(8) [A0A1(T+1)+B(T+1) landed] tail: 2 (skip on last tile)
// LDS [128][64] halves, slot^=(row&7) swizzle (conflict-free). Rect per-XCD chunking.
// NT must be even (K=4096 -> 64).
template<typename CT>
__global__ __launch_bounds__(512, 1) void gemm256(
    const unsigned short* __restrict__ A, int lda,
    const unsigned short* __restrict__ W, int ldw,
    CT* __restrict__ C, int ldc,
    int M, int N, int K)
{
    __shared__ unsigned short Asl[2][2][128 * 64];   // [buf][half][row*64 + col]
    __shared__ unsigned short Bsl[2][2][128 * 64];

    const int t = threadIdx.x;           // 0..511
    const int w = t >> 6, lane = t & 63;

    // rectangular per-XCD chunking
    const int gx = gridDim.x;
    const int nwg = gx * gridDim.y;
    const int chunk = nwg >> 3;
    const int orig = blockIdx.y * gx + blockIdx.x;
    const int xcd = orig & 7, idx = orig >> 3;
    const int rn = chunk >> 3;
    const int nrx = gx / rn;
    const int rx = xcd % nrx, ry = xcd / nrx;
    const int iy = idx / rn, ix = idx % rn;
    const int m0 = (ry * 8 + iy) * 256;
    const int n0 = (rx * rn + ix) * 256;

    const int wm = (w >> 2) * 128;
    const int wn = (w & 3) * 64;
    const int fr = lane & 15, hi = lane >> 4;

    f32x4 acc[8][4];
    #pragma unroll
    for (int i = 0; i < 8; ++i)
        #pragma unroll
        for (int j = 0; j < 4; ++j)
            acc[i][j] = (f32x4){0.f, 0.f, 0.f, 0.f};

    const int sl = t & 7;
    const int srw = (t >> 3) & 7;        // swizzle row bits
    const int wv512 = w * 512;

    auto STAGE_B = [&](int bufn, int k0, int u) {
        const int row = u * 64 + (t >> 3);                       // N-row 0..255
        const int scol = k0 + ((sl ^ srw) << 3);
        GLDS16(W + (size_t)(n0 + row) * ldw + scol,
               &Bsl[bufn][u >> 1][(u & 1) * 4096 + wv512]);
    };
    auto STAGE_A = [&](int bufn, int k0, int u) {
        const int half = w >> 2;
        const int row = half * 128 + u * 32 + ((t & 255) >> 3);  // M-row
        const int scol = k0 + ((sl ^ srw) << 3);
        GLDS16(A + (size_t)(m0 + row) * lda + scol,
               &Asl[bufn][half][u * 2048 + (w & 3) * 512]);
    };

    const int NT = K >> 6;   // even for all our launches

    // ---- prologue FIFO: B(T0)x4, A0A1(T0), A2A3(T0), B(T1)x4, A0A1(T1) = 14 loads
    STAGE_B(0, 0, 0); STAGE_B(0, 0, 1); STAGE_B(0, 0, 2); STAGE_B(0, 0, 3);
    STAGE_A(0, 0, 0); STAGE_A(0, 0, 1);
    STAGE_A(0, 0, 2); STAGE_A(0, 0, 3);
    STAGE_B(1, 64, 0); STAGE_B(1, 64, 1); STAGE_B(1, 64, 2); STAGE_B(1, 64, 3);
    STAGE_A(1, 64, 0); STAGE_A(1, 64, 1);
    asm volatile("s_waitcnt vmcnt(8)" ::: "memory");   // B(T0)+A0A1(T0) landed
    __builtin_amdgcn_s_barrier();
    __builtin_amdgcn_sched_barrier(0);

    short8 bAr[4][2], bBr[4][2];

    auto TILE = [&](int buf, short8 (&bc)[4][2], short8 (&bn)[4][2], int kt) {
        const bool p1 = kt + 1 < NT, p2 = kt + 2 < NT;
        const int k1 = (kt + 1) << 6, k2 = (kt + 2) << 6;
        const unsigned short* Ah  = Asl[buf][w >> 2];
        const unsigned short* Bc  = Bsl[buf][(w & 3) >> 1];
        const unsigned short* BhN = Bsl[buf ^ 1][(w & 3) >> 1];

        #pragma unroll
        for (int q = 0; q < 4; ++q) {
            // ---- reads (before barrier; latency hidden in barrier wait)
            if (kt == 0 && q == 0) {       // first tile: B-cur from LDS
                #pragma unroll
                for (int j = 0; j < 4; ++j) {
                    const int lr = (wn & 127) + j * 16 + fr, sz = lr & 7;
                    bc[j][0] = *(const short8*)&Bc[lr * 64 + (((0 + hi) ^ sz) << 3)];
                    bc[j][1] = *(const short8*)&Bc[lr * 64 + (((4 + hi) ^ sz) << 3)];
                }
            }
            short8 af[2][2];
            #pragma unroll
            for (int ii = 0; ii < 2; ++ii) {
                const int lr = q * 32 + ii * 16 + fr, sz = lr & 7;
                af[ii][0] = *(const short8*)&Ah[lr * 64 + (((0 + hi) ^ sz) << 3)];
                af[ii][1] = *(const short8*)&Ah[lr * 64 + (((4 + hi) ^ sz) << 3)];
            }
            if (p1 && q >= 2) {            // prefetch next tile's B-frags to regs
                #pragma unroll
                for (int jj = 0; jj < 2; ++jj) {
                    const int j = (q - 2) * 2 + jj;
                    const int lr = (wn & 127) + j * 16 + fr, sz = lr & 7;
                    bn[j][0] = *(const short8*)&BhN[lr * 64 + (((0 + hi) ^ sz) << 3)];
                    bn[j][1] = *(const short8*)&BhN[lr * 64 + (((4 + hi) ^ sz) << 3)];
                }
            }

            // ---- staggered stages
            if (q == 0)      { if (p1) { STAGE_A(buf ^ 1, k1, 2); STAGE_A(buf ^ 1, k1, 3); } }
            else if (q == 1) { if (p2) { STAGE_B(buf, k2, 0); STAGE_B(buf, k2, 1); } }
            else if (q == 2) { if (p2) { STAGE_B(buf, k2, 2); STAGE_B(buf, k2, 3); } }
            else             { if (p2) { STAGE_A(buf, k2, 0); STAGE_A(buf, k2, 1); } }

            __builtin_amdgcn_sched_barrier(0);
            __builtin_amdgcn_s_barrier();
            __builtin_amdgcn_sched_barrier(0);

            // ---- 16 MFMA (quadrant q); B operands already in registers
            __builtin_amdgcn_s_setprio(1);
            #pragma unroll
            for (int ii = 0; ii < 2; ++ii)
                #pragma unroll
                for (int j = 0; j < 4; ++j) {
                    acc[q * 2 + ii][j] = __builtin_amdgcn_mfma_f32_16x16x32_bf16(
                        af[ii][0], bc[j][0], acc[q * 2 + ii][j], 0, 0, 0);
                    acc[q * 2 + ii][j] = __builtin_amdgcn_mfma_f32_16x16x32_bf16(
                        af[ii][1], bc[j][1], acc[q * 2 + ii][j], 0, 0, 0);
                }
            __builtin_amdgcn_s_setprio(0);

            // ---- derived counted waits (after MFMA, before closing barrier)
            if (q == 1) {
                if (p2)      asm volatile("s_waitcnt vmcnt(6)" ::: "memory");
                else if (p1) asm volatile("s_waitcnt vmcnt(4)" ::: "memory");
                else         asm volatile("s_waitcnt vmcnt(0)" ::: "memory");
            } else if (q == 3 && p1) {
                if (p2) asm volatile("s_waitcnt vmcnt(8)" ::: "memory");
                else    asm volatile("s_waitcnt vmcnt(2)" ::: "memory");
            }
            __builtin_amdgcn_sched_barrier(0);
            __builtin_amdgcn_s_barrier();
            __builtin_amdgcn_sched_barrier(0);
        }
    };

    for (int kt = 0; kt < NT; kt += 2) {
        TILE(0, bAr, bBr, kt);
        TILE(1, bBr, bAr, kt + 1);
    }

    // epilogue: C/D layout col=lane&15, row=(lane>>4)*4+reg (verified)
    const int crow = (lane >> 4) * 4, ccol = lane & 15;
    #pragma unroll
    for (int i = 0; i < 8; ++i)
        #pragma unroll
        for (int j = 0; j < 4; ++j) {
            CT* cp = C + (size_t)(m0 + wm + i * 16 + crow) * ldc + (n0 + wn + j * 16 + ccol);
            #pragma unroll
            for (int r = 0; r < 4; ++r) {
                if constexpr (sizeof(CT) == 2)
                    cp[(size_t)r * ldc] = bf16bits(acc[i][j][r]);
                else
                    cp[(size_t)r * ldc] = acc[i][j][r];
            }
        }
}

// ---------------- MFMA flash attention: swapped 32x32x16, in-register softmax,
// LDS-shared double-buffered K/V with counted vmcnt (verified r8) ----------------
__global__ __launch_bounds__(256, 2) void flash_mfma32(
    const unsigned short* __restrict__ Qb, int ldq,   // rope'd, pre-scaled
    const unsigned short* __restrict__ Kb, int ldk,   // rope'd
    const unsigned short* __restrict__ Vt,            // [B*KVH][HD][SLEN]
    unsigned short* __restrict__ Ob)                  // [MROWS][DMODEL]
{
    __shared__ unsigned short Ks[2][64 * 128];   // [kv 64][d 128], rows 256B, swz (row&15)<<4
    __shared__ unsigned short Vs[2][128 * 64];   // [d 128][kv 64], rows 128B, swz (row&7)<<4

    const int t = threadIdx.x;
    const int wid = t >> 6, lane = t & 63;
    const int qt = (int)gridDim.x - 1 - (int)blockIdx.x;   // heavy blocks first
    const int bh = blockIdx.y;
    const int b = bh >> 5, h = bh & 31, kvh = h >> 2;
    const int lq = lane & 31;
    const int hl = lane >> 5;
    const int qw0 = qt * 128 + wid * 32;
    const int qg = qw0 + lq;
    const size_t qrowg = (size_t)b * SLEN + qg;

    const unsigned short* Kg0 = Kb + (size_t)b * SLEN * ldk + kvh * HD;
    const unsigned short* Vg0 = Vt + (size_t)(b * KVHEADS + kvh) * HD * SLEN;

    auto STAGE = [&](int buf, int kt) {   // 8 GLDS16 per thread
        const unsigned short* Kg = Kg0 + (size_t)kt * 64 * ldk;
        #pragma unroll
        for (int i = 0; i < 4; ++i) {
            int row = i * 16 + (t >> 4);
            int colel = ((((t & 15) << 4) ^ ((row & 15) << 4)) >> 1);
            GLDS16(Kg + (size_t)row * ldk + colel, &Ks[buf][i * 2048 + wid * 512]);
        }
        const unsigned short* Vg = Vg0 + kt * 64;
        #pragma unroll
        for (int i = 0; i < 4; ++i) {
            int row = i * 32 + (t >> 3);
            int colel = ((((t & 7) << 4) ^ ((row & 7) << 4)) >> 1);
            GLDS16(Vg + (size_t)row * SLEN + colel, &Vs[buf][i * 2048 + wid * 512]);
        }
    };

    STAGE(0, 0);
    short8 qf[8];
    {
        const unsigned short* qp = Qb + qrowg * ldq + h * HD + hl * 8;
        #pragma unroll
        for (int dt = 0; dt < 8; ++dt)
            qf[dt] = *(const short8*)(qp + dt * 16);
    }

    f32x16 accO[4];
    #pragma unroll
    for (int db = 0; db < 4; ++db)
        #pragma unroll
        for (int r = 0; r < 16; ++r) accO[db][r] = 0.f;
    float m_i = -INFINITY, l_i = 0.f;

    const int ntmax = 2 * qt + 2;   // uniform across waves
    int p = 0;
    for (int kt = 0; kt < ntmax; ++kt) {
        if (kt + 1 < ntmax) {
            STAGE(p ^ 1, kt + 1);
            asm volatile("s_waitcnt vmcnt(8)" ::: "memory");
        } else {
            asm volatile("s_waitcnt vmcnt(0)" ::: "memory");
        }
        __builtin_amdgcn_s_barrier();
        __builtin_amdgcn_sched_barrier(0);

        const unsigned short* Kp = Ks[p];
        const unsigned short* Vp = Vs[p];

        // ---- QK^T: S^T[kv 64][q 32], 16 MFMA
        f32x16 sc[2];
        #pragma unroll
        for (int blk = 0; blk < 2; ++blk) {
            #pragma unroll
            for (int r = 0; r < 16; ++r) sc[blk][r] = 0.f;
            __builtin_amdgcn_s_setprio(1);
            #pragma unroll
            for (int dt = 0; dt < 8; ++dt) {
                int krow = blk * 32 + lq;
                int kb = krow * 256 + ((dt * 32 + hl * 16) ^ ((krow & 15) << 4));
                short8 kf = *(const short8*)(Kp + (kb >> 1));
                sc[blk] = __builtin_amdgcn_mfma_f32_32x32x16_bf16(kf, qf[dt], sc[blk], 0, 0, 0);
            }
            __builtin_amdgcn_s_setprio(0);
        }

        // ---- causal mask
        if (kt * 64 + 63 > qw0) {
            #pragma unroll
            for (int blk = 0; blk < 2; ++blk)
                #pragma unroll
                for (int r = 0; r < 16; ++r) {
                    int kv = kt * 64 + blk * 32 + (r & 3) + 8 * (r >> 2) + 4 * hl;
                    if (kv > qg) sc[blk][r] = -INFINITY;
                }
        }

        // ---- row max (in-lane + one cross-half swap)
        float pmax = sc[0][0];
        #pragma unroll
        for (int r = 1; r < 16; ++r) pmax = fmaxf(pmax, sc[0][r]);
        #pragma unroll
        for (int r = 0; r < 16; ++r) pmax = fmaxf(pmax, sc[1][r]);
        {
            i32x2 mr = __builtin_amdgcn_permlane32_swap(__float_as_int(pmax), __float_as_int(pmax), false, false);
            pmax = fmaxf(__int_as_float(mr.x), __int_as_float(mr.y));
        }

        // ---- defer-max rescale (THR=8 log2 -> P<=256)
        if (!__all(pmax <= m_i + 8.0f)) {
            float mn = fmaxf(m_i, pmax);
            float al = exp2f(m_i - mn);
            m_i = mn;
            l_i *= al;
            #pragma unroll
            for (int db = 0; db < 4; ++db)
                #pragma unroll
                for (int r = 0; r < 16; ++r) accO[db][r] *= al;
        }

        // ---- exp + row sum
        float rs = 0.f;
        #pragma unroll
        for (int blk = 0; blk < 2; ++blk)
            #pragma unroll
            for (int r = 0; r < 16; ++r) {
                float pv = exp2f(sc[blk][r] - m_i);
                sc[blk][r] = pv;
                rs += pv;
            }
        {
            i32x2 sr = __builtin_amdgcn_permlane32_swap(__float_as_int(rs), __float_as_int(rs), false, false);
            rs = __int_as_float(sr.x) + __int_as_float(sr.y);
        }
        l_i += rs;

        // ---- pack P -> PV B-fragments in registers (verified r7)
        short8 pf[4];
        #pragma unroll
        for (int blk = 0; blk < 2; ++blk) {
            unsigned c01 = cvtpk(sc[blk][0],  sc[blk][1]);
            unsigned c23 = cvtpk(sc[blk][2],  sc[blk][3]);
            unsigned c45 = cvtpk(sc[blk][4],  sc[blk][5]);
            unsigned c67 = cvtpk(sc[blk][6],  sc[blk][7]);
            i32x2 sA = __builtin_amdgcn_permlane32_swap((int)c01, (int)c45, false, false);
            i32x2 sB = __builtin_amdgcn_permlane32_swap((int)c23, (int)c67, false, false);
            u32x4 f0 = {(unsigned)sA.x, (unsigned)sB.x, (unsigned)sA.y, (unsigned)sB.y};
            pf[blk * 2] = *(short8*)&f0;
            unsigned c89 = cvtpk(sc[blk][8],  sc[blk][9]);
            unsigned cab = cvtpk(sc[blk][10], sc[blk][11]);
            unsigned ccd = cvtpk(sc[blk][12], sc[blk][13]);
            unsigned cef = cvtpk(sc[blk][14], sc[blk][15]);
            i32x2 sC = __builtin_amdgcn_permlane32_swap((int)c89, (int)ccd, false, false);
            i32x2 sD = __builtin_amdgcn_permlane32_swap((int)cab, (int)cef, false, false);
            u32x4 f1 = {(unsigned)sC.x, (unsigned)sD.x, (unsigned)sC.y, (unsigned)sD.y};
            pf[blk * 2 + 1] = *(short8*)&f1;
        }

        // ---- PV: O^T[d][q] accum, 16 MFMA
        #pragma unroll
        for (int db = 0; db < 4; ++db) {
            __builtin_amdgcn_s_setprio(1);
            #pragma unroll
            for (int ks = 0; ks < 4; ++ks) {
                int vrow = db * 32 + lq;
                int vb = vrow * 128 + ((ks * 32 + hl * 16) ^ ((vrow & 7) << 4));
                short8 vf = *(const short8*)(Vp + (vb >> 1));
                accO[db] = __builtin_amdgcn_mfma_f32_32x32x16_bf16(vf, pf[ks], accO[db], 0, 0, 0);
            }
            __builtin_amdgcn_s_setprio(0);
        }

        __builtin_amdgcn_sched_barrier(0);
        __builtin_amdgcn_s_barrier();
        p ^= 1;
    }

    // ---- epilogue
    float inv = 1.0f / l_i;
    unsigned short* orow = Ob + qrowg * DMODEL + h * HD;
    #pragma unroll
    for (int db = 0; db < 4; ++db)
        #pragma unroll
        for (int rq = 0; rq < 4; ++rq) {
            unsigned w0 = cvtpk(accO[db][rq * 4 + 0] * inv, accO[db][rq * 4 + 1] * inv);
            unsigned w1 = cvtpk(accO[db][rq * 4 + 2] * inv, accO[db][rq * 4 + 3] * inv);
            uint2 pkd; pkd.x = w0; pkd.y = w1;
            *(uint2*)(orow + db * 32 + rq * 8 + hl * 4) = pkd;
        }
}

extern "C" void kernel_launch(void* const* d_in, const int* in_sizes, int n_in,
                              void* d_out, int out_size, void* d_ws, size_t ws_size,
                              hipStream_t stream) {
    const float* hs  = (const float*)d_in[0];
    const int*   pos = (const int*)d_in[1];
    const float* wq  = (const float*)d_in[2];
    const float* wk  = (const float*)d_in[3];
    const float* wv  = (const float*)d_in[4];
    const float* wo  = (const float*)d_in[5];
    float* out = (float*)d_out;

    char* ws = (char*)d_ws;
    unsigned short* hs_bf   = (unsigned short*)(ws);                        // 32 MB
    unsigned short* wqkv_bf = (unsigned short*)(ws + ((size_t)32  << 20));  // 48 MB [6144][4096]
    unsigned short* wo_bf   = (unsigned short*)(ws + ((size_t)80  << 20));  // 32 MB
    unsigned short* qkv_bf  = (unsigned short*)(ws + ((size_t)112 << 20));  // 48 MB [4096][6144]
    unsigned short* Vtb     = (unsigned short*)(ws + ((size_t)160 << 20));  // 8 MB
    unsigned short* Obf     = (unsigned short*)(ws + ((size_t)168 << 20));  // 32 MB
    float*          cosT    = (float*)(ws + ((size_t)200 << 20));           // 512 KB
    float*          sinT    = (float*)(ws + ((size_t)200 << 20) + (size_t)SLEN * 64 * 4);
    // total ~201 MB

    const long nHS = (long)MROWS * DMODEL;
    const long nWQ = (long)DMODEL * DMODEL;
    const long nWK = (long)KVDIM * DMODEL;

    rope_table_k<<<SLEN, 64, 0, stream>>>(pos, cosT, sinT);

    cast_k<<<nHS / 4 / 256, 256, 0, stream>>>(hs, hs_bf, nHS);
    cast_k<<<nWQ / 4 / 256, 256, 0, stream>>>(wq, wqkv_bf, nWQ);
    cast_k<<<nWK / 4 / 256, 256, 0, stream>>>(wk, wqkv_bf + (size_t)DMODEL * DMODEL, nWK);
    cast_k<<<nWK / 4 / 256, 256, 0, stream>>>(wv, wqkv_bf + (size_t)(DMODEL + KVDIM) * DMODEL, nWK);
    cast_k<<<nWQ / 4 / 256, 256, 0, stream>>>(wo, wo_bf, nWQ);

    // fused QKV projection: [4096][6144] bf16
    gemm256<unsigned short><<<dim3(NQKV/256, MROWS/256), 512, 0, stream>>>(
        hs_bf, DMODEL, wqkv_bf, DMODEL, qkv_bf, NQKV, MROWS, NQKV, DMODEL);

    // Q gets (1/sqrt(128)) * log2(e) folded in; K unscaled
    const float qmul = 0.088388347648318447f * 1.4426950408889634f;
    rope_bf_k<<<(MROWS * NHEADS  * 64) / 256, 256, 0, stream>>>(qkv_bf,          cosT, sinT, NHEADS,  NQKV, qmul);
    rope_bf_k<<<(MROWS * KVHEADS * 64) / 256, 256, 0, stream>>>(qkv_bf + DMODEL, cosT, sinT, KVHEADS, NQKV, 1.0f);
    vtrans_k<<<dim3(SLEN/64, BATCH*KVHEADS), 256, 0, stream>>>(qkv_bf + DMODEL + KVDIM, NQKV, Vtb);

    flash_mfma32<<<dim3(SLEN/128, BATCH*NHEADS), 256, 0, stream>>>(
        qkv_bf, NQKV, qkv_bf + DMODEL, NQKV, Vtb, Obf);

    gemm256<float><<<dim3(DMODEL/256, MROWS/256), 512, 0, stream>>>(
        Obf, DMODEL, wo_bf, DMODEL, out, DMODEL, MROWS, DMODEL, DMODEL);
}

// Round 15
// 569.257 us; speedup vs baseline: 1.1438x; 1.0453x over previous
//
#include <hip/hip_runtime.h>
#include <hip/hip_bf16.h>
#include <math.h>

typedef __attribute__((ext_vector_type(8))) short short8;
typedef __attribute__((ext_vector_type(4))) float f32x4;
typedef __attribute__((ext_vector_type(16))) float f32x16;
typedef __attribute__((ext_vector_type(4))) unsigned int u32x4;
typedef __attribute__((ext_vector_type(2))) int i32x2;

#define BATCH   2
#define SLEN    2048
#define DMODEL  4096
#define NHEADS  32
#define KVHEADS 8
#define HD      128
#define KVDIM   (KVHEADS*HD)   // 1024
#define MROWS   (BATCH*SLEN)   // 4096
#define NQKV    (DMODEL + 2*KVDIM)   // 6144

// async global->LDS, 16B per lane, dest = wave-uniform base + lane*16
#define GLDS16(gp, lp) __builtin_amdgcn_global_load_lds( \
    (const __attribute__((address_space(1))) void*)(gp), \
    (__attribute__((address_space(3))) void*)(lp), 16, 0, 0)

static __device__ __forceinline__ unsigned short bf16bits(float x) {
    __hip_bfloat16 h = __float2bfloat16(x);
    return *(unsigned short*)&h;
}
static __device__ __forceinline__ float bf2f(unsigned short u) {
    __hip_bfloat16 h = *(__hip_bfloat16*)&u;
    return __bfloat162float(h);
}
// v_cvt_pk_bf16_f32: lo=src0, hi=src1 (no builtin on gfx950)
static __device__ __forceinline__ unsigned cvtpk(float a, float b) {
    unsigned r;
    asm("v_cvt_pk_bf16_f32 %0, %1, %2" : "=v"(r) : "v"(a), "v"(b));
    return r;
}

// ---------------- fp32 -> bf16 cast ----------------
__global__ __launch_bounds__(256) void cast_k(const float* __restrict__ in,
                                              unsigned short* __restrict__ out, long n) {
    long i = ((long)blockIdx.x * 256 + threadIdx.x) * 4;
    if (i >= n) return;
    float4 v = *(const float4*)(in + i);
    union { unsigned short h[4]; uint2 u; } c;
    c.h[0] = bf16bits(v.x); c.h[1] = bf16bits(v.y);
    c.h[2] = bf16bits(v.z); c.h[3] = bf16bits(v.w);
    *(uint2*)(out + i) = c.u;
}

// ---------------- RoPE tables ----------------
__global__ void rope_table_k(const int* __restrict__ pos,
                             float* __restrict__ cosT, float* __restrict__ sinT) {
    int s = blockIdx.x;
    int d = threadIdx.x;
    float p = (float)pos[s];
    float inv = powf(10000.0f, -(float)(2 * d) / 128.0f);
    float ang = p * inv;
    cosT[s * 64 + d] = cosf(ang);
    sinT[s * 64 + d] = sinf(ang);
}

// ---------------- RoPE apply in-place on bf16, row stride ld ----------------
__global__ void rope_bf_k(unsigned short* __restrict__ x,
                          const float* __restrict__ cosT, const float* __restrict__ sinT,
                          int nh, int ld, float mul) {
    int idx = blockIdx.x * 256 + threadIdx.x;
    int d = idx & 63;
    int rest = idx >> 6;
    int h = rest % nh;
    int row = rest / nh;
    int s = row & (SLEN - 1);
    float c  = cosT[s * 64 + d] * mul;
    float sn = sinT[s * 64 + d] * mul;
    unsigned short* base = x + (size_t)row * ld + h * HD;
    float x1 = bf2f(base[d]), x2 = bf2f(base[d + 64]);
    base[d]      = bf16bits(x1 * c - x2 * sn);
    base[d + 64] = bf16bits(x2 * c + x1 * sn);
}

// ---------------- V transpose: bf16 [M][ldv] -> bf16 Vt[b*KVH+kvh][d=128][s=2048] ----------------
__global__ __launch_bounds__(256) void vtrans_k(const unsigned short* __restrict__ V, int ldv,
                                                unsigned short* __restrict__ Vt) {
    __shared__ unsigned short L[64][144];
    const int t = threadIdx.x;
    const int s0 = blockIdx.x * 64;
    const int bk = blockIdx.y;              // b*KVH + kvh
    const int b = bk >> 3, kvh = bk & 7;
    #pragma unroll
    for (int j = 0; j < 4; ++j) {
        int idx = t + j * 256;
        int row = idx >> 4;
        int c8  = (idx & 15) * 8;
        *(short8*)&L[row][c8] =
            *(const short8*)(V + ((size_t)b * SLEN + s0 + row) * ldv + kvh * HD + c8);
    }
    __syncthreads();
    {
        int d  = t >> 1;
        int sh = (t & 1) * 32;
        unsigned short tmp[32];
        #pragma unroll
        for (int j = 0; j < 32; ++j) tmp[j] = L[sh + j][d];
        unsigned short* dst = Vt + ((size_t)bk * HD + d) * SLEN + s0 + sh;
        #pragma unroll
        for (int j = 0; j < 4; ++j)
            *(short8*)(dst + j * 8) = *(const short8*)(tmp + j * 8);
    }
}

// ---------------- 256x256 bf16 MFMA GEMM-NT, BK=64, 8 waves ----------------
// r14 schedule with ONE barrier per phase (the r14 "opening" barrier was redundant:
// reads+stages precede it, so the previous phase's barrier already provides their
// guarantees; MFMA after it consumes only registers). Phase:
//   [reads | stages | derived vmcnt wait] -> SB,BAR,SB -> setprio MFMA setprio
// B-fragment PING-PONG: tile T's q2/q3 read tile T+1's B-frags from the other LDS
// buffer into bn regs -> q0 needs only 4 A-reads. Stagger (2 loads/thread/phase):
// q0: A2A3(T+1)->buf^1; q1: B0B1(T+2)->buf; q2: B2B3(T+2)->buf; q3: A0A1(T+2)->buf.
// Derived FIFO waits (positions/values identical to r14, now pre-barrier):
//   q1: vmcnt(6) [B(T+1)+A2A3(T) landed]   tail: 4 / 0
//   q3: vmcnt(8) [A0A1(T+1)+B(T+1) landed] tail: 2 (skip on last tile)
// WAR: every stage issues >=1 barrier after its target region's last global read.
// LDS [128][64] halves, slot^=(row&7) swizzle (conflict-free). Rect per-XCD chunking.
// NT must be even (K=4096 -> 64).
template<typename CT>
__global__ __launch_bounds__(512, 1) void gemm256(
    const unsigned short* __restrict__ A, int lda,
    const unsigned short* __restrict__ W, int ldw,
    CT* __restrict__ C, int ldc,
    int M, int N, int K)
{
    __shared__ unsigned short Asl[2][2][128 * 64];   // [buf][half][row*64 + col]
    __shared__ unsigned short Bsl[2][2][128 * 64];

    const int t = threadIdx.x;           // 0..511
    const int w = t >> 6, lane = t & 63;

    // rectangular per-XCD chunking
    const int gx = gridDim.x;
    const int nwg = gx * gridDim.y;
    const int chunk = nwg >> 3;
    const int orig = blockIdx.y * gx + blockIdx.x;
    const int xcd = orig & 7, idx = orig >> 3;
    const int rn = chunk >> 3;
    const int nrx = gx / rn;
    const int rx = xcd % nrx, ry = xcd / nrx;
    const int iy = idx / rn, ix = idx % rn;
    const int m0 = (ry * 8 + iy) * 256;
    const int n0 = (rx * rn + ix) * 256;

    const int wm = (w >> 2) * 128;
    const int wn = (w & 3) * 64;
    const int fr = lane & 15, hi = lane >> 4;

    f32x4 acc[8][4];
    #pragma unroll
    for (int i = 0; i < 8; ++i)
        #pragma unroll
        for (int j = 0; j < 4; ++j)
            acc[i][j] = (f32x4){0.f, 0.f, 0.f, 0.f};

    const int sl = t & 7;
    const int srw = (t >> 3) & 7;        // swizzle row bits
    const int wv512 = w * 512;

    auto STAGE_B = [&](int bufn, int k0, int u) {
        const int row = u * 64 + (t >> 3);                       // N-row 0..255
        const int scol = k0 + ((sl ^ srw) << 3);
        GLDS16(W + (size_t)(n0 + row) * ldw + scol,
               &Bsl[bufn][u >> 1][(u & 1) * 4096 + wv512]);
    };
    auto STAGE_A = [&](int bufn, int k0, int u) {
        const int half = w >> 2;
        const int row = half * 128 + u * 32 + ((t & 255) >> 3);  // M-row
        const int scol = k0 + ((sl ^ srw) << 3);
        GLDS16(A + (size_t)(m0 + row) * lda + scol,
               &Asl[bufn][half][u * 2048 + (w & 3) * 512]);
    };

    const int NT = K >> 6;   // even for all our launches

    // ---- prologue FIFO: B(T0)x4, A0A1(T0), A2A3(T0), B(T1)x4, A0A1(T1) = 14 loads
    STAGE_B(0, 0, 0); STAGE_B(0, 0, 1); STAGE_B(0, 0, 2); STAGE_B(0, 0, 3);
    STAGE_A(0, 0, 0); STAGE_A(0, 0, 1);
    STAGE_A(0, 0, 2); STAGE_A(0, 0, 3);
    STAGE_B(1, 64, 0); STAGE_B(1, 64, 1); STAGE_B(1, 64, 2); STAGE_B(1, 64, 3);
    STAGE_A(1, 64, 0); STAGE_A(1, 64, 1);
    asm volatile("s_waitcnt vmcnt(8)" ::: "memory");   // B(T0)+A0A1(T0) landed
    __builtin_amdgcn_s_barrier();
    __builtin_amdgcn_sched_barrier(0);

    short8 bAr[4][2], bBr[4][2];

    auto TILE = [&](int buf, short8 (&bc)[4][2], short8 (&bn)[4][2], int kt) {
        const bool p1 = kt + 1 < NT, p2 = kt + 2 < NT;
        const int k1 = (kt + 1) << 6, k2 = (kt + 2) << 6;
        const unsigned short* Ah  = Asl[buf][w >> 2];
        const unsigned short* Bc  = Bsl[buf][(w & 3) >> 1];
        const unsigned short* BhN = Bsl[buf ^ 1][(w & 3) >> 1];

        #pragma unroll
        for (int q = 0; q < 4; ++q) {
            // ---- reads (protected by previous phase's barrier)
            if (kt == 0 && q == 0) {       // first tile: B-cur from LDS
                #pragma unroll
                for (int j = 0; j < 4; ++j) {
                    const int lr = (wn & 127) + j * 16 + fr, sz = lr & 7;
                    bc[j][0] = *(const short8*)&Bc[lr * 64 + (((0 + hi) ^ sz) << 3)];
                    bc[j][1] = *(const short8*)&Bc[lr * 64 + (((4 + hi) ^ sz) << 3)];
                }
            }
            short8 af[2][2];
            #pragma unroll
            for (int ii = 0; ii < 2; ++ii) {
                const int lr = q * 32 + ii * 16 + fr, sz = lr & 7;
                af[ii][0] = *(const short8*)&Ah[lr * 64 + (((0 + hi) ^ sz) << 3)];
                af[ii][1] = *(const short8*)&Ah[lr * 64 + (((4 + hi) ^ sz) << 3)];
            }
            if (p1 && q >= 2) {            // prefetch next tile's B-frags to regs
                #pragma unroll
                for (int jj = 0; jj < 2; ++jj) {
                    const int j = (q - 2) * 2 + jj;
                    const int lr = (wn & 127) + j * 16 + fr, sz = lr & 7;
                    bn[j][0] = *(const short8*)&BhN[lr * 64 + (((0 + hi) ^ sz) << 3)];
                    bn[j][1] = *(const short8*)&BhN[lr * 64 + (((4 + hi) ^ sz) << 3)];
                }
            }

            // ---- staggered stages
            if (q == 0)      { if (p1) { STAGE_A(buf ^ 1, k1, 2); STAGE_A(buf ^ 1, k1, 3); } }
            else if (q == 1) { if (p2) { STAGE_B(buf, k2, 0); STAGE_B(buf, k2, 1); } }
            else if (q == 2) { if (p2) { STAGE_B(buf, k2, 2); STAGE_B(buf, k2, 3); } }
            else             { if (p2) { STAGE_A(buf, k2, 0); STAGE_A(buf, k2, 1); } }

            // ---- derived counted waits (pre-barrier; FIFO positions = r14)
            if (q == 1) {
                if (p2)      asm volatile("s_waitcnt vmcnt(6)" ::: "memory");
                else if (p1) asm volatile("s_waitcnt vmcnt(4)" ::: "memory");
                else         asm volatile("s_waitcnt vmcnt(0)" ::: "memory");
            } else if (q == 3 && p1) {
                if (p2) asm volatile("s_waitcnt vmcnt(8)" ::: "memory");
                else    asm volatile("s_waitcnt vmcnt(2)" ::: "memory");
            }

            // ---- single barrier per phase
            __builtin_amdgcn_sched_barrier(0);
            __builtin_amdgcn_s_barrier();
            __builtin_amdgcn_sched_barrier(0);

            // ---- 16 MFMA (quadrant q); B operands already in registers
            __builtin_amdgcn_s_setprio(1);
            #pragma unroll
            for (int ii = 0; ii < 2; ++ii)
                #pragma unroll
                for (int j = 0; j < 4; ++j) {
                    acc[q * 2 + ii][j] = __builtin_amdgcn_mfma_f32_16x16x32_bf16(
                        af[ii][0], bc[j][0], acc[q * 2 + ii][j], 0, 0, 0);
                    acc[q * 2 + ii][j] = __builtin_amdgcn_mfma_f32_16x16x32_bf16(
                        af[ii][1], bc[j][1], acc[q * 2 + ii][j], 0, 0, 0);
                }
            __builtin_amdgcn_s_setprio(0);
            __builtin_amdgcn_sched_barrier(0);
        }
    };

    for (int kt = 0; kt < NT; kt += 2) {
        TILE(0, bAr, bBr, kt);
        TILE(1, bBr, bAr, kt + 1);
    }

    // epilogue: C/D layout col=lane&15, row=(lane>>4)*4+reg (verified)
    const int crow = (lane >> 4) * 4, ccol = lane & 15;
    #pragma unroll
    for (int i = 0; i < 8; ++i)
        #pragma unroll
        for (int j = 0; j < 4; ++j) {
            CT* cp = C + (size_t)(m0 + wm + i * 16 + crow) * ldc + (n0 + wn + j * 16 + ccol);
            #pragma unroll
            for (int r = 0; r < 4; ++r) {
                if constexpr (sizeof(CT) == 2)
                    cp[(size_t)r * ldc] = bf16bits(acc[i][j][r]);
                else
                    cp[(size_t)r * ldc] = acc[i][j][r];
            }
        }
}

// ---------------- MFMA flash attention: swapped 32x32x16, in-register softmax,
// LDS-shared double-buffered K/V with counted vmcnt (verified r8) ----------------
__global__ __launch_bounds__(256, 2) void flash_mfma32(
    const unsigned short* __restrict__ Qb, int ldq,   // rope'd, pre-scaled
    const unsigned short* __restrict__ Kb, int ldk,   // rope'd
    const unsigned short* __restrict__ Vt,            // [B*KVH][HD][SLEN]
    unsigned short* __restrict__ Ob)                  // [MROWS][DMODEL]
{
    __shared__ unsigned short Ks[2][64 * 128];   // [kv 64][d 128], rows 256B, swz (row&15)<<4
    __shared__ unsigned short Vs[2][128 * 64];   // [d 128][kv 64], rows 128B, swz (row&7)<<4

    const int t = threadIdx.x;
    const int wid = t >> 6, lane = t & 63;
    const int qt = (int)gridDim.x - 1 - (int)blockIdx.x;   // heavy blocks first
    const int bh = blockIdx.y;
    const int b = bh >> 5, h = bh & 31, kvh = h >> 2;
    const int lq = lane & 31;
    const int hl = lane >> 5;
    const int qw0 = qt * 128 + wid * 32;
    const int qg = qw0 + lq;
    const size_t qrowg = (size_t)b * SLEN + qg;

    const unsigned short* Kg0 = Kb + (size_t)b * SLEN * ldk + kvh * HD;
    const unsigned short* Vg0 = Vt + (size_t)(b * KVHEADS + kvh) * HD * SLEN;

    auto STAGE = [&](int buf, int kt) {   // 8 GLDS16 per thread
        const unsigned short* Kg = Kg0 + (size_t)kt * 64 * ldk;
        #pragma unroll
        for (int i = 0; i < 4; ++i) {
            int row = i * 16 + (t >> 4);
            int colel = ((((t & 15) << 4) ^ ((row & 15) << 4)) >> 1);
            GLDS16(Kg + (size_t)row * ldk + colel, &Ks[buf][i * 2048 + wid * 512]);
        }
        const unsigned short* Vg = Vg0 + kt * 64;
        #pragma unroll
        for (int i = 0; i < 4; ++i) {
            int row = i * 32 + (t >> 3);
            int colel = ((((t & 7) << 4) ^ ((row & 7) << 4)) >> 1);
            GLDS16(Vg + (size_t)row * SLEN + colel, &Vs[buf][i * 2048 + wid * 512]);
        }
    };

    STAGE(0, 0);
    short8 qf[8];
    {
        const unsigned short* qp = Qb + qrowg * ldq + h * HD + hl * 8;
        #pragma unroll
        for (int dt = 0; dt < 8; ++dt)
            qf[dt] = *(const short8*)(qp + dt * 16);
    }

    f32x16 accO[4];
    #pragma unroll
    for (int db = 0; db < 4; ++db)
        #pragma unroll
        for (int r = 0; r < 16; ++r) accO[db][r] = 0.f;
    float m_i = -INFINITY, l_i = 0.f;

    const int ntmax = 2 * qt + 2;   // uniform across waves
    int p = 0;
    for (int kt = 0; kt < ntmax; ++kt) {
        if (kt + 1 < ntmax) {
            STAGE(p ^ 1, kt + 1);
            asm volatile("s_waitcnt vmcnt(8)" ::: "memory");
        } else {
            asm volatile("s_waitcnt vmcnt(0)" ::: "memory");
        }
        __builtin_amdgcn_s_barrier();
        __builtin_amdgcn_sched_barrier(0);

        const unsigned short* Kp = Ks[p];
        const unsigned short* Vp = Vs[p];

        // ---- QK^T: S^T[kv 64][q 32], 16 MFMA
        f32x16 sc[2];
        #pragma unroll
        for (int blk = 0; blk < 2; ++blk) {
            #pragma unroll
            for (int r = 0; r < 16; ++r) sc[blk][r] = 0.f;
            __builtin_amdgcn_s_setprio(1);
            #pragma unroll
            for (int dt = 0; dt < 8; ++dt) {
                int krow = blk * 32 + lq;
                int kb = krow * 256 + ((dt * 32 + hl * 16) ^ ((krow & 15) << 4));
                short8 kf = *(const short8*)(Kp + (kb >> 1));
                sc[blk] = __builtin_amdgcn_mfma_f32_32x32x16_bf16(kf, qf[dt], sc[blk], 0, 0, 0);
            }
            __builtin_amdgcn_s_setprio(0);
        }

        // ---- causal mask
        if (kt * 64 + 63 > qw0) {
            #pragma unroll
            for (int blk = 0; blk < 2; ++blk)
                #pragma unroll
                for (int r = 0; r < 16; ++r) {
                    int kv = kt * 64 + blk * 32 + (r & 3) + 8 * (r >> 2) + 4 * hl;
                    if (kv > qg) sc[blk][r] = -INFINITY;
                }
        }

        // ---- row max (in-lane + one cross-half swap)
        float pmax = sc[0][0];
        #pragma unroll
        for (int r = 1; r < 16; ++r) pmax = fmaxf(pmax, sc[0][r]);
        #pragma unroll
        for (int r = 0; r < 16; ++r) pmax = fmaxf(pmax, sc[1][r]);
        {
            i32x2 mr = __builtin_amdgcn_permlane32_swap(__float_as_int(pmax), __float_as_int(pmax), false, false);
            pmax = fmaxf(__int_as_float(mr.x), __int_as_float(mr.y));
        }

        // ---- defer-max rescale (THR=8 log2 -> P<=256)
        if (!__all(pmax <= m_i + 8.0f)) {
            float mn = fmaxf(m_i, pmax);
            float al = exp2f(m_i - mn);
            m_i = mn;
            l_i *= al;
            #pragma unroll
            for (int db = 0; db < 4; ++db)
                #pragma unroll
                for (int r = 0; r < 16; ++r) accO[db][r] *= al;
        }

        // ---- exp + row sum
        float rs = 0.f;
        #pragma unroll
        for (int blk = 0; blk < 2; ++blk)
            #pragma unroll
            for (int r = 0; r < 16; ++r) {
                float pv = exp2f(sc[blk][r] - m_i);
                sc[blk][r] = pv;
                rs += pv;
            }
        {
            i32x2 sr = __builtin_amdgcn_permlane32_swap(__float_as_int(rs), __float_as_int(rs), false, false);
            rs = __int_as_float(sr.x) + __int_as_float(sr.y);
        }
        l_i += rs;

        // ---- pack P -> PV B-fragments in registers (verified r7)
        short8 pf[4];
        #pragma unroll
        for (int blk = 0; blk < 2; ++blk) {
            unsigned c01 = cvtpk(sc[blk][0],  sc[blk][1]);
            unsigned c23 = cvtpk(sc[blk][2],  sc[blk][3]);
            unsigned c45 = cvtpk(sc[blk][4],  sc[blk][5]);
            unsigned c67 = cvtpk(sc[blk][6],  sc[blk][7]);
            i32x2 sA = __builtin_amdgcn_permlane32_swap((int)c01, (int)c45, false, false);
            i32x2 sB = __builtin_amdgcn_permlane32_swap((int)c23, (int)c67, false, false);
            u32x4 f0 = {(unsigned)sA.x, (unsigned)sB.x, (unsigned)sA.y, (unsigned)sB.y};
            pf[blk * 2] = *(short8*)&f0;
            unsigned c89 = cvtpk(sc[blk][8],  sc[blk][9]);
            unsigned cab = cvtpk(sc[blk][10], sc[blk][11]);
            unsigned ccd = cvtpk(sc[blk][12], sc[blk][13]);
            unsigned cef = cvtpk(sc[blk][14], sc[blk][15]);
            i32x2 sC = __builtin_amdgcn_permlane32_swap((int)c89, (int)ccd, false, false);
            i32x2 sD = __builtin_amdgcn_permlane32_swap((int)cab, (int)cef, false, false);
            u32x4 f1 = {(unsigned)sC.x, (unsigned)sD.x, (unsigned)sC.y, (unsigned)sD.y};
            pf[blk * 2 + 1] = *(short8*)&f1;
        }

        // ---- PV: O^T[d][q] accum, 16 MFMA
        #pragma unroll
        for (int db = 0; db < 4; ++db) {
            __builtin_amdgcn_s_setprio(1);
            #pragma unroll
            for (int ks = 0; ks < 4; ++ks) {
                int vrow = db * 32 + lq;
                int vb = vrow * 128 + ((ks * 32 + hl * 16) ^ ((vrow & 7) << 4));
                short8 vf = *(const short8*)(Vp + (vb >> 1));
                accO[db] = __builtin_amdgcn_mfma_f32_32x32x16_bf16(vf, pf[ks], accO[db], 0, 0, 0);
            }
            __builtin_amdgcn_s_setprio(0);
        }

        __builtin_amdgcn_sched_barrier(0);
        __builtin_amdgcn_s_barrier();
        p ^= 1;
    }

    // ---- epilogue
    float inv = 1.0f / l_i;
    unsigned short* orow = Ob + qrowg * DMODEL + h * HD;
    #pragma unroll
    for (int db = 0; db < 4; ++db)
        #pragma unroll
        for (int rq = 0; rq < 4; ++rq) {
            unsigned w0 = cvtpk(accO[db][rq * 4 + 0] * inv, accO[db][rq * 4 + 1] * inv);
            unsigned w1 = cvtpk(accO[db][rq * 4 + 2] * inv, accO[db][rq * 4 + 3] * inv);
            uint2 pkd; pkd.x = w0; pkd.y = w1;
            *(uint2*)(orow + db * 32 + rq * 8 + hl * 4) = pkd;
        }
}

extern "C" void kernel_launch(void* const* d_in, const int* in_sizes, int n_in,
                              void* d_out, int out_size, void* d_ws, size_t ws_size,
                              hipStream_t stream) {
    const float* hs  = (const float*)d_in[0];
    const int*   pos = (const int*)d_in[1];
    const float* wq  = (const float*)d_in[2];
    const float* wk  = (const float*)d_in[3];
    const float* wv  = (const float*)d_in[4];
    const float* wo  = (const float*)d_in[5];
    float* out = (float*)d_out;

    char* ws = (char*)d_ws;
    unsigned short* hs_bf   = (unsigned short*)(ws);                        // 32 MB
    unsigned short* wqkv_bf = (unsigned short*)(ws + ((size_t)32  << 20));  // 48 MB [6144][4096]
    unsigned short* wo_bf   = (unsigned short*)(ws + ((size_t)80  << 20));  // 32 MB
    unsigned short* qkv_bf  = (unsigned short*)(ws + ((size_t)112 << 20));  // 48 MB [4096][6144]
    unsigned short* Vtb     = (unsigned short*)(ws + ((size_t)160 << 20));  // 8 MB
    unsigned short* Obf     = (unsigned short*)(ws + ((size_t)168 << 20));  // 32 MB
    float*          cosT    = (float*)(ws + ((size_t)200 << 20));           // 512 KB
    float*          sinT    = (float*)(ws + ((size_t)200 << 20) + (size_t)SLEN * 64 * 4);
    // total ~201 MB

    const long nHS = (long)MROWS * DMODEL;
    const long nWQ = (long)DMODEL * DMODEL;
    const long nWK = (long)KVDIM * DMODEL;

    rope_table_k<<<SLEN, 64, 0, stream>>>(pos, cosT, sinT);

    cast_k<<<nHS / 4 / 256, 256, 0, stream>>>(hs, hs_bf, nHS);
    cast_k<<<nWQ / 4 / 256, 256, 0, stream>>>(wq, wqkv_bf, nWQ);
    cast_k<<<nWK / 4 / 256, 256, 0, stream>>>(wk, wqkv_bf + (size_t)DMODEL * DMODEL, nWK);
    cast_k<<<nWK / 4 / 256, 256, 0, stream>>>(wv, wqkv_bf + (size_t)(DMODEL + KVDIM) * DMODEL, nWK);
    cast_k<<<nWQ / 4 / 256, 256, 0, stream>>>(wo, wo_bf, nWQ);

    // fused QKV projection: [4096][6144] bf16
    gemm256<unsigned short><<<dim3(NQKV/256, MROWS/256), 512, 0, stream>>>(
        hs_bf, DMODEL, wqkv_bf, DMODEL, qkv_bf, NQKV, MROWS, NQKV, DMODEL);

    // Q gets (1/sqrt(128)) * log2(e) folded in; K unscaled
    const float qmul = 0.088388347648318447f * 1.4426950408889634f;
    rope_bf_k<<<(MROWS * NHEADS  * 64) / 256, 256, 0, stream>>>(qkv_bf,          cosT, sinT, NHEADS,  NQKV, qmul);
    rope_bf_k<<<(MROWS * KVHEADS * 64) / 256, 256, 0, stream>>>(qkv_bf + DMODEL, cosT, sinT, KVHEADS, NQKV, 1.0f);
    vtrans_k<<<dim3(SLEN/64, BATCH*KVHEADS), 256, 0, stream>>>(qkv_bf + DMODEL + KVDIM, NQKV, Vtb);

    flash_mfma32<<<dim3(SLEN/128, BATCH*NHEADS), 256, 0, stream>>>(
        qkv_bf, NQKV, qkv_bf + DMODEL, NQKV, Vtb, Obf);

    gemm256<float><<<dim3(DMODEL/256, MROWS/256), 512, 0, stream>>>(
        Obf, DMODEL, wo_bf, DMODEL, out, DMODEL, MROWS, DMODEL, DMODEL);
}